// Round 6
// baseline (389.283 us; speedup 1.0000x reference)
//
#include <hip/hip_runtime.h>

typedef short s16x8 __attribute__((ext_vector_type(8)));
typedef short s16x4 __attribute__((ext_vector_type(4)));
typedef float f32x4 __attribute__((ext_vector_type(4)));

#define MFMA32(a, b, c) __builtin_amdgcn_mfma_f32_16x16x32_bf16((a), (b), (c), 0, 0, 0)

// async global->LDS DMA, 16B per lane; LDS dest = wave-uniform base + lane*16
__device__ __forceinline__ void stage16(const unsigned short* g, unsigned short* l) {
#if defined(__HIP_DEVICE_COMPILE__)
  __builtin_amdgcn_global_load_lds((const __attribute__((address_space(1))) unsigned int*)g,
                                   (__attribute__((address_space(3))) unsigned int*)l, 16, 0, 0);
#endif
}

// fp32 -> bf16 bits, round-nearest-even
__device__ __forceinline__ unsigned short f2b(float f) {
  unsigned int u = __builtin_bit_cast(unsigned int, f);
  unsigned int r = u + 0x7FFFu + ((u >> 16) & 1u);
  return (unsigned short)(r >> 16);
}
// pack two fp32 into bf16x2 (RNE). Device: 2x round-add + 1x v_perm_b32
// (bytes {2,3} of each rounded value == >>16). Bit-identical to f2b pair.
__device__ __forceinline__ unsigned int pk2(float a, float b) {
#if defined(__HIP_DEVICE_COMPILE__)
  unsigned int ua = __builtin_bit_cast(unsigned int, a);
  unsigned int ub = __builtin_bit_cast(unsigned int, b);
  ua += 0x7FFFu + ((ua >> 16) & 1u);
  ub += 0x7FFFu + ((ub >> 16) & 1u);
  return __builtin_amdgcn_perm(ub, ua, 0x07060302u);  // {ub.b3, ub.b2, ua.b3, ua.b2}
#else
  return (unsigned int)f2b(a) | ((unsigned int)f2b(b) << 16);
#endif
}
__device__ __forceinline__ float fast_exp2(float x) {
#if defined(__HIP_DEVICE_COMPILE__) && __has_builtin(__builtin_amdgcn_exp2f)
  return __builtin_amdgcn_exp2f(x);
#else
  return exp2f(x);
#endif
}

// ---------------------------------------------------------------------------
// fp32 -> bf16 cast, 8 elems/thread. n8 = n/8.
// ---------------------------------------------------------------------------
__global__ __launch_bounds__(256) void castq(const float* __restrict__ X,
                                             unsigned short* __restrict__ Y) {
  int i = blockIdx.x * 256 + threadIdx.x;
  float4 f0 = ((const float4*)X)[i * 2];
  float4 f1 = ((const float4*)X)[i * 2 + 1];
  uint4 u;
  u.x = pk2(f0.x, f0.y);
  u.y = pk2(f0.z, f0.w);
  u.z = pk2(f1.x, f1.y);
  u.w = pk2(f1.z, f1.w);
  ((uint4*)Y)[i] = u;
}

// ---------------------------------------------------------------------------
// Weight transpose + cast: T[n][k] = bf16(W[k][n]), 1024x1024, z selects matrix
// ---------------------------------------------------------------------------
__global__ void wtrans(const float* __restrict__ W0, const float* __restrict__ W1,
                       const float* __restrict__ W2, const float* __restrict__ W3,
                       unsigned short* __restrict__ T0, unsigned short* __restrict__ T1,
                       unsigned short* __restrict__ T2, unsigned short* __restrict__ T3) {
  const float* W;
  unsigned short* T;
  switch (blockIdx.z) {
    case 0: W = W0; T = T0; break;
    case 1: W = W1; T = T1; break;
    case 2: W = W2; T = T2; break;
    default: W = W3; T = T3; break;
  }
  __shared__ float tile[32][33];
  const int n0 = blockIdx.x << 5;
  const int k0 = blockIdx.y << 5;
  const int tx = threadIdx.x;
  const int ty = threadIdx.y;
#pragma unroll
  for (int j = 0; j < 4; ++j)
    tile[ty + 8 * j][tx] = W[(size_t)(k0 + ty + 8 * j) * 1024 + n0 + tx];
  __syncthreads();
#pragma unroll
  for (int j = 0; j < 4; ++j)
    T[(size_t)(n0 + ty + 8 * j) * 1024 + k0 + tx] = f2b(tile[tx][ty + 8 * j]);
}

// ---------------------------------------------------------------------------
// GEMM: C[8192,1024] = A[8192,1024]bf16 @ Bt[1024,1024]^T + bias
// T3 2-phase pipeline (same recipe as the verified flash loop): double-
// buffered 128x32 tiles; issue K-step k+1's global_load_lds into buf^1
// BEFORE computing buf, then one {s_waitcnt vmcnt(0); s_barrier} per step —
// DMA latency hides under the 16-MFMA compute phase instead of a cold drain.
// Occupancy raised to 3 blocks/CU (96KB LDS, ~170 VGPR/wave budget).
// MODE 0: store bf16 to [B,H,S,D] (q,k) | 1: bf16 [B,H,D,S] (v) | 2: fp32 row-major
// ---------------------------------------------------------------------------
template <int MODE>
__global__ __launch_bounds__(256, 3) void gemm_bt(const unsigned short* __restrict__ A,
                                                  const unsigned short* __restrict__ Bt,
                                                  const float* __restrict__ bias,
                                                  void* __restrict__ Cout, float oscale) {
  __shared__ __align__(16) unsigned short As[2 * 128 * 32];
  __shared__ __align__(16) unsigned short Bs[2 * 128 * 32];
  const int n0 = blockIdx.x * 128;
  const int m0 = blockIdx.y * 128;
  const int tid = threadIdx.x;
  const int w = tid >> 6;
  const int lane = tid & 63;
  const int lr = lane & 15;
  const int lg = lane >> 4;
  const int wm = (w >> 1) << 6;
  const int wn = (w & 1) << 6;

  // staging: wave w, inst i in {0,1}: rows i*64 + w*16 + (lane>>2), seg = lane&3
  const int srow = w * 16 + (lane >> 2);
  const int sseg = lane & 3;
  const unsigned short* Ag0 = A + (size_t)(m0 + srow) * 1024 + sseg * 8;
  const unsigned short* Ag1 = A + (size_t)(m0 + 64 + srow) * 1024 + sseg * 8;
  const unsigned short* Bg0 = Bt + (size_t)(n0 + srow) * 1024 + sseg * 8;
  const unsigned short* Bg1 = Bt + (size_t)(n0 + 64 + srow) * 1024 + sseg * 8;
  unsigned short* Al0 = &As[(w * 16) * 32];
  unsigned short* Al1 = &As[(64 + w * 16) * 32];
  unsigned short* Bl0 = &Bs[(w * 16) * 32];
  unsigned short* Bl1 = &Bs[(64 + w * 16) * 32];

  f32x4 acc[4][4];
#pragma unroll
  for (int i = 0; i < 4; ++i)
#pragma unroll
    for (int j = 0; j < 4; ++j) {
      f32x4 z = {0.f, 0.f, 0.f, 0.f};
      acc[i][j] = z;
    }

  // prologue: stage K-step 0 into buffer 0, drain, sync
  stage16(Ag0, Al0);
  stage16(Ag1, Al1);
  stage16(Bg0, Bl0);
  stage16(Bg1, Bl1);
  asm volatile("s_waitcnt vmcnt(0)\n\ts_barrier" ::: "memory");

  int cur = 0;
  for (int k0 = 0; k0 < 1024; k0 += 32) {
    // issue next K-step's DMA into the other buffer (in flight during compute)
    if (k0 + 32 < 1024) {
      const int nb = (cur ^ 1) * 4096;
      stage16(Ag0 + k0 + 32, Al0 + nb);
      stage16(Ag1 + k0 + 32, Al1 + nb);
      stage16(Bg0 + k0 + 32, Bl0 + nb);
      stage16(Bg1 + k0 + 32, Bl1 + nb);
    }
    const int cb = cur * 4096;
    s16x8 af[4], bfr[4];
#pragma unroll
    for (int mt = 0; mt < 4; ++mt)
      af[mt] = *(const s16x8*)&As[cb + (wm + mt * 16 + lr) * 32 + lg * 8];
#pragma unroll
    for (int nt = 0; nt < 4; ++nt)
      bfr[nt] = *(const s16x8*)&Bs[cb + (wn + nt * 16 + lr) * 32 + lg * 8];
#pragma unroll
    for (int mt = 0; mt < 4; ++mt)
#pragma unroll
      for (int nt = 0; nt < 4; ++nt)
        acc[mt][nt] = MFMA32(af[mt], bfr[nt], acc[mt][nt]);
    // drain next-step DMA (covered by compute above) + separate buf reuse
    asm volatile("s_waitcnt vmcnt(0)\n\ts_barrier" ::: "memory");
    cur ^= 1;
  }

  float bcol[4];
#pragma unroll
  for (int nt = 0; nt < 4; ++nt) bcol[nt] = bias[n0 + wn + nt * 16 + lr];

#pragma unroll
  for (int mt = 0; mt < 4; ++mt)
#pragma unroll
    for (int nt = 0; nt < 4; ++nt)
#pragma unroll
      for (int r = 0; r < 4; ++r) {
        float v = (acc[mt][nt][r] + bcol[nt]) * oscale;
        int row = m0 + wm + mt * 16 + lg * 4 + r;  // token index (b*2048+s)
        int col = n0 + wn + nt * 16 + lr;          // feature index (h*64+d)
        if constexpr (MODE == 0) {
          int b = row >> 11, s = row & 2047, hh = col >> 6, d = col & 63;
          ((unsigned short*)Cout)[(((size_t)(b * 16 + hh) * 2048 + s) << 6) + d] = f2b(v);
        } else if constexpr (MODE == 1) {
          int b = row >> 11, s = row & 2047, hh = col >> 6, d = col & 63;
          ((unsigned short*)Cout)[(((size_t)(b * 16 + hh) * 64 + d) << 11) + s] = f2b(v);
        } else {
          ((float*)Cout)[(size_t)row * 1024 + col] = v;
        }
      }
}

// ---------------------------------------------------------------------------
// Flash attention, transposed-S, double-buffered LDS K/V (T3 2-phase pipeline).
// Per tile: issue next tile's global_load_lds into buf[cur^1] FIRST, compute
// on buf[cur], then one {s_waitcnt vmcnt(0); s_barrier} — the next tile's DMA
// is in flight during the whole compute phase instead of being drained cold.
// Hazards: WAR on buf[cur] (next iter's stage) separated by the end barrier;
// RAW on buf[cur^1] drained by the same vmcnt(0)+barrier. One barrier/tile.
// PV + l-sum on 16x16x32 MFMA (round-4-verified slot-permutation layout).
// ---------------------------------------------------------------------------
__global__ __launch_bounds__(256, 4) void flash_attn(const unsigned short* __restrict__ qh,
                                                     const unsigned short* __restrict__ kh,
                                                     const unsigned short* __restrict__ vt,
                                                     const float* __restrict__ mask,
                                                     unsigned short* __restrict__ ctx) {
  const float c2 = 1.4426950408889634e9f;  // 1e9*log2(e)
  const int id = blockIdx.x;
  const int bh = id & 63;
  const int qtile = id >> 6;
  const int b = bh >> 4;
  const int h = bh & 15;
  const int q0 = qtile << 7;
  const int tid = threadIdx.x;
  const int w = tid >> 6;
  const int lane = tid & 63;
  const int lr = lane & 15;
  const int lg = lane >> 4;

  __shared__ __align__(16) unsigned short Ks[2 * 64 * 64];  // [buf][key][d], swizzled segs
  __shared__ __align__(16) unsigned short Vs[2 * 64 * 64];  // [buf][d][key], swizzled segs

  const unsigned short* qbase = qh + ((size_t)bh * 2048 + q0 + w * 32) * 64;
  const unsigned short* kbase = kh + (size_t)bh * 2048 * 64;
  const unsigned short* vbase = vt + (size_t)bh * 64 * 2048;
  const float* mbase = mask + b * 2048;

  const int rowc = lane >> 3;
  const int gseg = (lane & 7) ^ rowc;
  const unsigned short* kg0 = kbase + (size_t)(w * 16 + rowc) * 64 + gseg * 8;
  const unsigned short* kg1 = kbase + (size_t)(w * 16 + 8 + rowc) * 64 + gseg * 8;
  const unsigned short* vg0 = vbase + (size_t)(w * 16 + rowc) * 2048 + gseg * 8;
  const unsigned short* vg1 = vbase + (size_t)(w * 16 + 8 + rowc) * 2048 + gseg * 8;
  unsigned short* kl0 = &Ks[(w * 16 + 0) * 64];
  unsigned short* kl1 = &Ks[(w * 16 + 8) * 64];
  unsigned short* vl0 = &Vs[(w * 16 + 0) * 64];
  unsigned short* vl1 = &Vs[(w * 16 + 8) * 64];

  s16x8 qf[2][2];
#pragma unroll
  for (int qt = 0; qt < 2; ++qt)
#pragma unroll
    for (int kk = 0; kk < 2; ++kk)
      qf[qt][kk] = *(const s16x8*)(qbase + (qt * 16 + lr) * 64 + kk * 32 + lg * 8);

  const s16x8 ones8 = {(short)0x3F80, (short)0x3F80, (short)0x3F80, (short)0x3F80,
                       (short)0x3F80, (short)0x3F80, (short)0x3F80, (short)0x3F80};

  f32x4 o_acc[2][4];
  f32x4 l_acc[2];
#pragma unroll
  for (int qt = 0; qt < 2; ++qt) {
    f32x4 z = {0.f, 0.f, 0.f, 0.f};
    l_acc[qt] = z;
#pragma unroll
    for (int dt = 0; dt < 4; ++dt) o_acc[qt][dt] = z;
  }

  // prologue: stage tile 0 into buffer 0, drain, sync
  stage16(kg0, kl0);
  stage16(kg1, kl1);
  stage16(vg0, vl0);
  stage16(vg1, vl1);
  asm volatile("s_waitcnt vmcnt(0)\n\ts_barrier" ::: "memory");

  int cur = 0;
  for (int t0 = 0; t0 < 2048; t0 += 64) {
    // issue next tile's DMA into the other buffer (in flight during compute)
    if (t0 + 64 < 2048) {
      const int nb = (cur ^ 1) * 4096;
      stage16(kg0 + (size_t)(t0 + 64) * 64, kl0 + nb);
      stage16(kg1 + (size_t)(t0 + 64) * 64, kl1 + nb);
      stage16(vg0 + (t0 + 64), vl0 + nb);
      stage16(vg1 + (t0 + 64), vl1 + nb);
    }
    float4 mk[4];
#pragma unroll
    for (int kt = 0; kt < 4; ++kt) mk[kt] = *(const float4*)(mbase + t0 + kt * 16 + lg * 4);

    const int cb = cur * 4096;
    const int sw = lr & 7;
    // scores -> exp2 -> packed bf16 pairs.
    // pw[kt][qt][u]: keys kt*16 + lg*4 + {2u, 2u+1}, query = lr
    unsigned int pw[4][2][2];
#pragma unroll
    for (int kt = 0; kt < 4; ++kt) {
      const int krow = kt * 16 + lr;
      s16x8 kf0 = *(const s16x8*)&Ks[cb + krow * 64 + ((lg ^ sw) * 8)];
      s16x8 kf1 = *(const s16x8*)&Ks[cb + krow * 64 + (((4 + lg) ^ sw) * 8)];
      float ml0 = mk[kt].x * c2, ml1 = mk[kt].y * c2;
      float ml2 = mk[kt].z * c2, ml3 = mk[kt].w * c2;
#pragma unroll
      for (int qt = 0; qt < 2; ++qt) {
        f32x4 s = {0.f, 0.f, 0.f, 0.f};
        s = MFMA32(kf0, qf[qt][0], s);
        s = MFMA32(kf1, qf[qt][1], s);
        pw[kt][qt][0] = pk2(fast_exp2(s[0] - ml0), fast_exp2(s[1] - ml1));
        pw[kt][qt][1] = pk2(fast_exp2(s[2] - ml2), fast_exp2(s[3] - ml3));
      }
    }

    // PV + l-sum on MFMA32. Chunk c covers keys 32c..32c+31.
    // B position (lg,j) <-> key 32c + (j>=4)*16 + lg*4 + (j&3); V reads match.
#pragma unroll
    for (int c = 0; c < 2; ++c) {
      s16x8 pb[2];
#pragma unroll
      for (int qt = 0; qt < 2; ++qt) {
        uint4 u;
        u.x = pw[2 * c][qt][0];
        u.y = pw[2 * c][qt][1];
        u.z = pw[2 * c + 1][qt][0];
        u.w = pw[2 * c + 1][qt][1];
        pb[qt] = __builtin_bit_cast(s16x8, u);
        l_acc[qt] = MFMA32(ones8, pb[qt], l_acc[qt]);
      }
      const int plo = ((c << 2) | (lg >> 1)) ^ sw;
      const int phi = ((c << 2) | 2 | (lg >> 1)) ^ sw;
      const int sub = (lg & 1) * 4;
#pragma unroll
      for (int dt = 0; dt < 4; ++dt) {
        const int d = dt * 16 + lr;
        s16x4 vlo = *(const s16x4*)&Vs[cb + d * 64 + plo * 8 + sub];
        s16x4 vhi = *(const s16x4*)&Vs[cb + d * 64 + phi * 8 + sub];
        s16x8 vf = __builtin_shufflevector(vlo, vhi, 0, 1, 2, 3, 4, 5, 6, 7);
#pragma unroll
        for (int qt = 0; qt < 2; ++qt) o_acc[qt][dt] = MFMA32(vf, pb[qt], o_acc[qt][dt]);
      }
    }

    // drain next-tile DMA (covered by compute above) + separate buf reuse
    asm volatile("s_waitcnt vmcnt(0)\n\ts_barrier" ::: "memory");
    cur ^= 1;
  }

#pragma unroll
  for (int qt = 0; qt < 2; ++qt) {
    float inv = 1.0f / l_acc[qt][0];
    int q = q0 + w * 32 + qt * 16 + lr;
    unsigned short* cp = ctx + ((size_t)(b * 2048 + q) * 16 + h) * 64 + lg * 4;
#pragma unroll
    for (int dt = 0; dt < 4; ++dt) {
      f32x4 o = o_acc[qt][dt];
      uint2 u;
      u.x = pk2(o[0] * inv, o[1] * inv);
      u.y = pk2(o[2] * inv, o[3] * inv);
      *(uint2*)(cp + dt * 16) = u;
    }
  }
}

// ---------------------------------------------------------------------------
// Launch pipeline. Workspace layout (72 MB):
//   0: wqt 2MB | 2: wkt | 4: wvt | 6: wot          (bf16 W^T [N,K])
//   8: qh 16MB [B,H,S,D] | 24: kh | 40: vt [B,H,D,S]
//   56: shared 16MB region: bf16-cast scratch (Q/K/V, sequential, stream-
//       ordered disjoint lifetimes) and later ctx [B,S,H,D] from flash.
// ---------------------------------------------------------------------------
extern "C" void kernel_launch(void* const* d_in, const int* in_sizes, int n_in,
                              void* d_out, int out_size, void* d_ws, size_t ws_size,
                              hipStream_t stream) {
  (void)in_sizes; (void)n_in; (void)out_size; (void)ws_size;
  const float* Q = (const float*)d_in[0];
  const float* K = (const float*)d_in[1];
  const float* V = (const float*)d_in[2];
  const float* mask = (const float*)d_in[3];
  const float* Wq = (const float*)d_in[4];
  const float* bq = (const float*)d_in[5];
  const float* Wk = (const float*)d_in[6];
  const float* bk = (const float*)d_in[7];
  const float* Wv = (const float*)d_in[8];
  const float* bv = (const float*)d_in[9];
  const float* Wo = (const float*)d_in[10];
  const float* bo = (const float*)d_in[11];

  char* ws = (char*)d_ws;
  unsigned short* wqt = (unsigned short*)(ws + (size_t)0);
  unsigned short* wkt = (unsigned short*)(ws + ((size_t)2 << 20));
  unsigned short* wvt = (unsigned short*)(ws + ((size_t)4 << 20));
  unsigned short* wot = (unsigned short*)(ws + ((size_t)6 << 20));
  unsigned short* qhb = (unsigned short*)(ws + ((size_t)8 << 20));
  unsigned short* khb = (unsigned short*)(ws + ((size_t)24 << 20));
  unsigned short* vtb = (unsigned short*)(ws + ((size_t)40 << 20));
  unsigned short* tmp = (unsigned short*)(ws + ((size_t)56 << 20));  // cast scratch / ctx
  unsigned short* ctx = tmp;

  wtrans<<<dim3(32, 32, 4), dim3(32, 8), 0, stream>>>(Wq, Wk, Wv, Wo, wqt, wkt, wvt, wot);

  const float qscale = 0.18033688011112042f;  // log2(e)/8, folded into Q projection
  dim3 gg(8, 64), bb(256);
  const int castBlocks = (8192 * 1024) / (256 * 8);  // 4096

  castq<<<castBlocks, 256, 0, stream>>>(Q, tmp);
  gemm_bt<0><<<gg, bb, 0, stream>>>(tmp, wqt, bq, qhb, qscale);
  castq<<<castBlocks, 256, 0, stream>>>(K, tmp);
  gemm_bt<0><<<gg, bb, 0, stream>>>(tmp, wkt, bk, khb, 1.0f);
  castq<<<castBlocks, 256, 0, stream>>>(V, tmp);
  gemm_bt<1><<<gg, bb, 0, stream>>>(tmp, wvt, bv, vtb, 1.0f);

  flash_attn<<<dim3(1024), dim3(256), 0, stream>>>(qhb, khb, vtb, mask, ctx);

  gemm_bt<2><<<gg, bb, 0, stream>>>(ctx, wot, bo, d_out, 1.0f);
}

// Round 7
// 379.755 us; speedup vs baseline: 1.0251x; 1.0251x over previous
//
#include <hip/hip_runtime.h>

typedef short s16x8 __attribute__((ext_vector_type(8)));
typedef short s16x4 __attribute__((ext_vector_type(4)));
typedef float f32x4 __attribute__((ext_vector_type(4)));

#define MFMA32(a, b, c) __builtin_amdgcn_mfma_f32_16x16x32_bf16((a), (b), (c), 0, 0, 0)

// async global->LDS DMA, 16B per lane; LDS dest = wave-uniform base + lane*16
__device__ __forceinline__ void stage16(const unsigned short* g, unsigned short* l) {
#if defined(__HIP_DEVICE_COMPILE__)
  __builtin_amdgcn_global_load_lds((const __attribute__((address_space(1))) unsigned int*)g,
                                   (__attribute__((address_space(3))) unsigned int*)l, 16, 0, 0);
#endif
}

// fp32 -> bf16 bits, round-nearest-even
__device__ __forceinline__ unsigned short f2b(float f) {
  unsigned int u = __builtin_bit_cast(unsigned int, f);
  unsigned int r = u + 0x7FFFu + ((u >> 16) & 1u);
  return (unsigned short)(r >> 16);
}
// pack two fp32 into bf16x2 (RNE). Device: 2x round-add + 1x v_perm_b32
// (bytes {2,3} of each rounded value == >>16). Bit-identical to f2b pair.
__device__ __forceinline__ unsigned int pk2(float a, float b) {
#if defined(__HIP_DEVICE_COMPILE__)
  unsigned int ua = __builtin_bit_cast(unsigned int, a);
  unsigned int ub = __builtin_bit_cast(unsigned int, b);
  ua += 0x7FFFu + ((ua >> 16) & 1u);
  ub += 0x7FFFu + ((ub >> 16) & 1u);
  return __builtin_amdgcn_perm(ub, ua, 0x07060302u);  // {ub.b3, ub.b2, ua.b3, ua.b2}
#else
  return (unsigned int)f2b(a) | ((unsigned int)f2b(b) << 16);
#endif
}
__device__ __forceinline__ float fast_exp2(float x) {
#if defined(__HIP_DEVICE_COMPILE__) && __has_builtin(__builtin_amdgcn_exp2f)
  return __builtin_amdgcn_exp2f(x);
#else
  return exp2f(x);
#endif
}

// ---------------------------------------------------------------------------
// Weight transpose + cast: T[n][k] = bf16(W[k][n]), 1024x1024, z selects matrix
// ---------------------------------------------------------------------------
__global__ void wtrans(const float* __restrict__ W0, const float* __restrict__ W1,
                       const float* __restrict__ W2, const float* __restrict__ W3,
                       unsigned short* __restrict__ T0, unsigned short* __restrict__ T1,
                       unsigned short* __restrict__ T2, unsigned short* __restrict__ T3) {
  const float* W;
  unsigned short* T;
  switch (blockIdx.z) {
    case 0: W = W0; T = T0; break;
    case 1: W = W1; T = T1; break;
    case 2: W = W2; T = T2; break;
    default: W = W3; T = T3; break;
  }
  __shared__ float tile[32][33];
  const int n0 = blockIdx.x << 5;
  const int k0 = blockIdx.y << 5;
  const int tx = threadIdx.x;
  const int ty = threadIdx.y;
#pragma unroll
  for (int j = 0; j < 4; ++j)
    tile[ty + 8 * j][tx] = W[(size_t)(k0 + ty + 8 * j) * 1024 + n0 + tx];
  __syncthreads();
#pragma unroll
  for (int j = 0; j < 4; ++j)
    T[(size_t)(n0 + ty + 8 * j) * 1024 + k0 + tx] = f2b(tile[tx][ty + 8 * j]);
}

// ---------------------------------------------------------------------------
// Fused QKV projection GEMM, one dispatch (grid.z in {0,1,2} selects Q/K/V).
// C[8192,1024] = bf16(A_fp32[8192,1024]) @ Wt[1024,1024]^T + bias.
// A is read DIRECTLY as fp32 (no separate cast pass): per K-step each lane
// loads 2x float4, converts via pk2 (bit-identical to the old castq), and
// ds_write_b128s into the same LDS layout the DMA produced. B (weights)
// stays on global_load_lds. 2-phase pipeline: issue next-step A-loads+B-DMA,
// compute current, convert+write next A, then {vmcnt(0) lgkmcnt(0); barrier}.
// z=0,1 store bf16 [B,H,S,D]; z=2 stores bf16 [B,H,D,S] (V transposed).
// ---------------------------------------------------------------------------
__global__ __launch_bounds__(256, 3) void gemm_qkv(
    const float* __restrict__ Qf, const float* __restrict__ Kf, const float* __restrict__ Vf,
    const unsigned short* __restrict__ Wqt, const unsigned short* __restrict__ Wkt,
    const unsigned short* __restrict__ Wvt, const float* __restrict__ bq,
    const float* __restrict__ bk, const float* __restrict__ bv,
    unsigned short* __restrict__ qh, unsigned short* __restrict__ kh,
    unsigned short* __restrict__ vtb, float qscale) {
  const float* A;
  const unsigned short* Bt;
  const float* bias;
  unsigned short* Cout;
  float oscale = 1.0f;
  int vmode = 0;
  switch (blockIdx.z) {
    case 0: A = Qf; Bt = Wqt; bias = bq; Cout = qh; oscale = qscale; break;
    case 1: A = Kf; Bt = Wkt; bias = bk; Cout = kh; break;
    default: A = Vf; Bt = Wvt; bias = bv; Cout = vtb; vmode = 1; break;
  }
  __shared__ __align__(16) unsigned short As[2 * 128 * 32];
  __shared__ __align__(16) unsigned short Bs[2 * 128 * 32];
  const int n0 = blockIdx.x * 128;
  const int m0 = blockIdx.y * 128;
  const int tid = threadIdx.x;
  const int w = tid >> 6;
  const int lane = tid & 63;
  const int lr = lane & 15;
  const int lg = lane >> 4;
  const int wm = (w >> 1) << 6;
  const int wn = (w & 1) << 6;

  // staging geometry (per wave, halves i=0,1): row = i*64 + w*16 + (lane>>2),
  // 16B segment = lane&3. LDS byte offset within half = lane*16.
  const int srow = w * 16 + (lane >> 2);
  const int sseg = lane & 3;
  const float* Ag0 = A + (size_t)(m0 + srow) * 1024 + sseg * 8;
  const float* Ag1 = A + (size_t)(m0 + 64 + srow) * 1024 + sseg * 8;
  const unsigned short* Bg0 = Bt + (size_t)(n0 + srow) * 1024 + sseg * 8;
  const unsigned short* Bg1 = Bt + (size_t)(n0 + 64 + srow) * 1024 + sseg * 8;
  unsigned short* Bl0 = &Bs[(w * 16) * 32];
  unsigned short* Bl1 = &Bs[(64 + w * 16) * 32];
  // per-lane A ds_write targets (element offsets within a buffer)
  const int aoff0 = (w * 16) * 32 + lane * 8;
  const int aoff1 = (64 + w * 16) * 32 + lane * 8;

  f32x4 acc[4][4];
#pragma unroll
  for (int i = 0; i < 4; ++i)
#pragma unroll
    for (int j = 0; j < 4; ++j) {
      f32x4 z = {0.f, 0.f, 0.f, 0.f};
      acc[i][j] = z;
    }

  // prologue: stage K-step 0 into buffer 0 (A via regs+cvt, B via DMA)
  {
    float4 a0lo = *(const float4*)Ag0;
    float4 a0hi = *(const float4*)(Ag0 + 4);
    float4 a1lo = *(const float4*)Ag1;
    float4 a1hi = *(const float4*)(Ag1 + 4);
    stage16(Bg0, Bl0);
    stage16(Bg1, Bl1);
    uint4 u0, u1;
    u0.x = pk2(a0lo.x, a0lo.y); u0.y = pk2(a0lo.z, a0lo.w);
    u0.z = pk2(a0hi.x, a0hi.y); u0.w = pk2(a0hi.z, a0hi.w);
    u1.x = pk2(a1lo.x, a1lo.y); u1.y = pk2(a1lo.z, a1lo.w);
    u1.z = pk2(a1hi.x, a1hi.y); u1.w = pk2(a1hi.z, a1hi.w);
    *(uint4*)&As[aoff0] = u0;
    *(uint4*)&As[aoff1] = u1;
  }
  asm volatile("s_waitcnt vmcnt(0) lgkmcnt(0)\n\ts_barrier" ::: "memory");

  int cur = 0;
  for (int k0 = 0; k0 < 1024; k0 += 32) {
    const bool next = (k0 + 32) < 1024;
    float4 a0lo, a0hi, a1lo, a1hi;
    if (next) {
      a0lo = *(const float4*)(Ag0 + k0 + 32);
      a0hi = *(const float4*)(Ag0 + k0 + 36);
      a1lo = *(const float4*)(Ag1 + k0 + 32);
      a1hi = *(const float4*)(Ag1 + k0 + 36);
      const int nb = (cur ^ 1) * 4096;
      stage16(Bg0 + k0 + 32, Bl0 + nb);
      stage16(Bg1 + k0 + 32, Bl1 + nb);
    }
    const int cb = cur * 4096;
    s16x8 af[4], bfr[4];
#pragma unroll
    for (int mt = 0; mt < 4; ++mt)
      af[mt] = *(const s16x8*)&As[cb + (wm + mt * 16 + lr) * 32 + lg * 8];
#pragma unroll
    for (int nt = 0; nt < 4; ++nt)
      bfr[nt] = *(const s16x8*)&Bs[cb + (wn + nt * 16 + lr) * 32 + lg * 8];
#pragma unroll
    for (int mt = 0; mt < 4; ++mt)
#pragma unroll
      for (int nt = 0; nt < 4; ++nt)
        acc[mt][nt] = MFMA32(af[mt], bfr[nt], acc[mt][nt]);
    if (next) {
      const int nb = (cur ^ 1) * 4096;
      uint4 u0, u1;
      u0.x = pk2(a0lo.x, a0lo.y); u0.y = pk2(a0lo.z, a0lo.w);
      u0.z = pk2(a0hi.x, a0hi.y); u0.w = pk2(a0hi.z, a0hi.w);
      u1.x = pk2(a1lo.x, a1lo.y); u1.y = pk2(a1lo.z, a1lo.w);
      u1.z = pk2(a1hi.x, a1hi.y); u1.w = pk2(a1hi.z, a1hi.w);
      *(uint4*)&As[nb + aoff0] = u0;
      *(uint4*)&As[nb + aoff1] = u1;
    }
    // B-DMA (untracked by compiler) + A ds_writes must be visible before the
    // next iteration's reads in ALL waves.
    asm volatile("s_waitcnt vmcnt(0) lgkmcnt(0)\n\ts_barrier" ::: "memory");
    cur ^= 1;
  }

  float bcol[4];
#pragma unroll
  for (int nt = 0; nt < 4; ++nt) bcol[nt] = bias[n0 + wn + nt * 16 + lr];

  if (vmode == 0) {
#pragma unroll
    for (int mt = 0; mt < 4; ++mt)
#pragma unroll
      for (int nt = 0; nt < 4; ++nt)
#pragma unroll
        for (int r = 0; r < 4; ++r) {
          float v = (acc[mt][nt][r] + bcol[nt]) * oscale;
          int row = m0 + wm + mt * 16 + lg * 4 + r;  // token (b*2048+s)
          int col = n0 + wn + nt * 16 + lr;          // feature (h*64+d)
          int b = row >> 11, s = row & 2047, hh = col >> 6, d = col & 63;
          Cout[(((size_t)(b * 16 + hh) * 2048 + s) << 6) + d] = f2b(v);
        }
  } else {
#pragma unroll
    for (int mt = 0; mt < 4; ++mt)
#pragma unroll
      for (int nt = 0; nt < 4; ++nt)
#pragma unroll
        for (int r = 0; r < 4; ++r) {
          float v = acc[mt][nt][r] + bcol[nt];
          int row = m0 + wm + mt * 16 + lg * 4 + r;
          int col = n0 + wn + nt * 16 + lr;
          int b = row >> 11, s = row & 2047, hh = col >> 6, d = col & 63;
          Cout[(((size_t)(b * 16 + hh) * 64 + d) << 11) + s] = f2b(v);
        }
  }
}

// ---------------------------------------------------------------------------
// Output GEMM (Wo): C[8192,1024]fp32 = ctx[8192,1024]bf16 @ Wot^T + bias.
// Round-6 2-phase structure, bf16 A via global_load_lds. MODE 2 store only.
// ---------------------------------------------------------------------------
__global__ __launch_bounds__(256, 3) void gemm_out(const unsigned short* __restrict__ A,
                                                   const unsigned short* __restrict__ Bt,
                                                   const float* __restrict__ bias,
                                                   float* __restrict__ Cout) {
  __shared__ __align__(16) unsigned short As[2 * 128 * 32];
  __shared__ __align__(16) unsigned short Bs[2 * 128 * 32];
  const int n0 = blockIdx.x * 128;
  const int m0 = blockIdx.y * 128;
  const int tid = threadIdx.x;
  const int w = tid >> 6;
  const int lane = tid & 63;
  const int lr = lane & 15;
  const int lg = lane >> 4;
  const int wm = (w >> 1) << 6;
  const int wn = (w & 1) << 6;

  const int srow = w * 16 + (lane >> 2);
  const int sseg = lane & 3;
  const unsigned short* Ag0 = A + (size_t)(m0 + srow) * 1024 + sseg * 8;
  const unsigned short* Ag1 = A + (size_t)(m0 + 64 + srow) * 1024 + sseg * 8;
  const unsigned short* Bg0 = Bt + (size_t)(n0 + srow) * 1024 + sseg * 8;
  const unsigned short* Bg1 = Bt + (size_t)(n0 + 64 + srow) * 1024 + sseg * 8;
  unsigned short* Al0 = &As[(w * 16) * 32];
  unsigned short* Al1 = &As[(64 + w * 16) * 32];
  unsigned short* Bl0 = &Bs[(w * 16) * 32];
  unsigned short* Bl1 = &Bs[(64 + w * 16) * 32];

  f32x4 acc[4][4];
#pragma unroll
  for (int i = 0; i < 4; ++i)
#pragma unroll
    for (int j = 0; j < 4; ++j) {
      f32x4 z = {0.f, 0.f, 0.f, 0.f};
      acc[i][j] = z;
    }

  stage16(Ag0, Al0);
  stage16(Ag1, Al1);
  stage16(Bg0, Bl0);
  stage16(Bg1, Bl1);
  asm volatile("s_waitcnt vmcnt(0)\n\ts_barrier" ::: "memory");

  int cur = 0;
  for (int k0 = 0; k0 < 1024; k0 += 32) {
    if (k0 + 32 < 1024) {
      const int nb = (cur ^ 1) * 4096;
      stage16(Ag0 + k0 + 32, Al0 + nb);
      stage16(Ag1 + k0 + 32, Al1 + nb);
      stage16(Bg0 + k0 + 32, Bl0 + nb);
      stage16(Bg1 + k0 + 32, Bl1 + nb);
    }
    const int cb = cur * 4096;
    s16x8 af[4], bfr[4];
#pragma unroll
    for (int mt = 0; mt < 4; ++mt)
      af[mt] = *(const s16x8*)&As[cb + (wm + mt * 16 + lr) * 32 + lg * 8];
#pragma unroll
    for (int nt = 0; nt < 4; ++nt)
      bfr[nt] = *(const s16x8*)&Bs[cb + (wn + nt * 16 + lr) * 32 + lg * 8];
#pragma unroll
    for (int mt = 0; mt < 4; ++mt)
#pragma unroll
      for (int nt = 0; nt < 4; ++nt)
        acc[mt][nt] = MFMA32(af[mt], bfr[nt], acc[mt][nt]);
    asm volatile("s_waitcnt vmcnt(0)\n\ts_barrier" ::: "memory");
    cur ^= 1;
  }

  float bcol[4];
#pragma unroll
  for (int nt = 0; nt < 4; ++nt) bcol[nt] = bias[n0 + wn + nt * 16 + lr];

#pragma unroll
  for (int mt = 0; mt < 4; ++mt)
#pragma unroll
    for (int nt = 0; nt < 4; ++nt)
#pragma unroll
      for (int r = 0; r < 4; ++r) {
        float v = acc[mt][nt][r] + bcol[nt];
        int row = m0 + wm + mt * 16 + lg * 4 + r;
        int col = n0 + wn + nt * 16 + lr;
        Cout[(size_t)row * 1024 + col] = v;
      }
}

// ---------------------------------------------------------------------------
// Flash attention, transposed-S, double-buffered LDS K/V (T3 2-phase pipeline).
// PV + l-sum on 16x16x32 MFMA (round-4-verified slot-permutation layout).
// ---------------------------------------------------------------------------
__global__ __launch_bounds__(256, 4) void flash_attn(const unsigned short* __restrict__ qh,
                                                     const unsigned short* __restrict__ kh,
                                                     const unsigned short* __restrict__ vt,
                                                     const float* __restrict__ mask,
                                                     unsigned short* __restrict__ ctx) {
  const float c2 = 1.4426950408889634e9f;  // 1e9*log2(e)
  const int id = blockIdx.x;
  const int bh = id & 63;
  const int qtile = id >> 6;
  const int b = bh >> 4;
  const int h = bh & 15;
  const int q0 = qtile << 7;
  const int tid = threadIdx.x;
  const int w = tid >> 6;
  const int lane = tid & 63;
  const int lr = lane & 15;
  const int lg = lane >> 4;

  __shared__ __align__(16) unsigned short Ks[2 * 64 * 64];  // [buf][key][d], swizzled segs
  __shared__ __align__(16) unsigned short Vs[2 * 64 * 64];  // [buf][d][key], swizzled segs

  const unsigned short* qbase = qh + ((size_t)bh * 2048 + q0 + w * 32) * 64;
  const unsigned short* kbase = kh + (size_t)bh * 2048 * 64;
  const unsigned short* vbase = vt + (size_t)bh * 64 * 2048;
  const float* mbase = mask + b * 2048;

  const int rowc = lane >> 3;
  const int gseg = (lane & 7) ^ rowc;
  const unsigned short* kg0 = kbase + (size_t)(w * 16 + rowc) * 64 + gseg * 8;
  const unsigned short* kg1 = kbase + (size_t)(w * 16 + 8 + rowc) * 64 + gseg * 8;
  const unsigned short* vg0 = vbase + (size_t)(w * 16 + rowc) * 2048 + gseg * 8;
  const unsigned short* vg1 = vbase + (size_t)(w * 16 + 8 + rowc) * 2048 + gseg * 8;
  unsigned short* kl0 = &Ks[(w * 16 + 0) * 64];
  unsigned short* kl1 = &Ks[(w * 16 + 8) * 64];
  unsigned short* vl0 = &Vs[(w * 16 + 0) * 64];
  unsigned short* vl1 = &Vs[(w * 16 + 8) * 64];

  s16x8 qf[2][2];
#pragma unroll
  for (int qt = 0; qt < 2; ++qt)
#pragma unroll
    for (int kk = 0; kk < 2; ++kk)
      qf[qt][kk] = *(const s16x8*)(qbase + (qt * 16 + lr) * 64 + kk * 32 + lg * 8);

  const s16x8 ones8 = {(short)0x3F80, (short)0x3F80, (short)0x3F80, (short)0x3F80,
                       (short)0x3F80, (short)0x3F80, (short)0x3F80, (short)0x3F80};

  f32x4 o_acc[2][4];
  f32x4 l_acc[2];
#pragma unroll
  for (int qt = 0; qt < 2; ++qt) {
    f32x4 z = {0.f, 0.f, 0.f, 0.f};
    l_acc[qt] = z;
#pragma unroll
    for (int dt = 0; dt < 4; ++dt) o_acc[qt][dt] = z;
  }

  // prologue: stage tile 0 into buffer 0, drain, sync
  stage16(kg0, kl0);
  stage16(kg1, kl1);
  stage16(vg0, vl0);
  stage16(vg1, vl1);
  asm volatile("s_waitcnt vmcnt(0)\n\ts_barrier" ::: "memory");

  int cur = 0;
  for (int t0 = 0; t0 < 2048; t0 += 64) {
    // issue next tile's DMA into the other buffer (in flight during compute)
    if (t0 + 64 < 2048) {
      const int nb = (cur ^ 1) * 4096;
      stage16(kg0 + (size_t)(t0 + 64) * 64, kl0 + nb);
      stage16(kg1 + (size_t)(t0 + 64) * 64, kl1 + nb);
      stage16(vg0 + (t0 + 64), vl0 + nb);
      stage16(vg1 + (t0 + 64), vl1 + nb);
    }
    float4 mk[4];
#pragma unroll
    for (int kt = 0; kt < 4; ++kt) mk[kt] = *(const float4*)(mbase + t0 + kt * 16 + lg * 4);

    const int cb = cur * 4096;
    const int sw = lr & 7;
    // scores -> exp2 -> packed bf16 pairs.
    // pw[kt][qt][u]: keys kt*16 + lg*4 + {2u, 2u+1}, query = lr
    unsigned int pw[4][2][2];
#pragma unroll
    for (int kt = 0; kt < 4; ++kt) {
      const int krow = kt * 16 + lr;
      s16x8 kf0 = *(const s16x8*)&Ks[cb + krow * 64 + ((lg ^ sw) * 8)];
      s16x8 kf1 = *(const s16x8*)&Ks[cb + krow * 64 + (((4 + lg) ^ sw) * 8)];
      float ml0 = mk[kt].x * c2, ml1 = mk[kt].y * c2;
      float ml2 = mk[kt].z * c2, ml3 = mk[kt].w * c2;
#pragma unroll
      for (int qt = 0; qt < 2; ++qt) {
        f32x4 s = {0.f, 0.f, 0.f, 0.f};
        s = MFMA32(kf0, qf[qt][0], s);
        s = MFMA32(kf1, qf[qt][1], s);
        pw[kt][qt][0] = pk2(fast_exp2(s[0] - ml0), fast_exp2(s[1] - ml1));
        pw[kt][qt][1] = pk2(fast_exp2(s[2] - ml2), fast_exp2(s[3] - ml3));
      }
    }

    // PV + l-sum on MFMA32. Chunk c covers keys 32c..32c+31.
    // B position (lg,j) <-> key 32c + (j>=4)*16 + lg*4 + (j&3); V reads match.
#pragma unroll
    for (int c = 0; c < 2; ++c) {
      s16x8 pb[2];
#pragma unroll
      for (int qt = 0; qt < 2; ++qt) {
        uint4 u;
        u.x = pw[2 * c][qt][0];
        u.y = pw[2 * c][qt][1];
        u.z = pw[2 * c + 1][qt][0];
        u.w = pw[2 * c + 1][qt][1];
        pb[qt] = __builtin_bit_cast(s16x8, u);
        l_acc[qt] = MFMA32(ones8, pb[qt], l_acc[qt]);
      }
      const int plo = ((c << 2) | (lg >> 1)) ^ sw;
      const int phi = ((c << 2) | 2 | (lg >> 1)) ^ sw;
      const int sub = (lg & 1) * 4;
#pragma unroll
      for (int dt = 0; dt < 4; ++dt) {
        const int d = dt * 16 + lr;
        s16x4 vlo = *(const s16x4*)&Vs[cb + d * 64 + plo * 8 + sub];
        s16x4 vhi = *(const s16x4*)&Vs[cb + d * 64 + phi * 8 + sub];
        s16x8 vf = __builtin_shufflevector(vlo, vhi, 0, 1, 2, 3, 4, 5, 6, 7);
#pragma unroll
        for (int qt = 0; qt < 2; ++qt) o_acc[qt][dt] = MFMA32(vf, pb[qt], o_acc[qt][dt]);
      }
    }

    // drain next-tile DMA (covered by compute above) + separate buf reuse
    asm volatile("s_waitcnt vmcnt(0)\n\ts_barrier" ::: "memory");
    cur ^= 1;
  }

#pragma unroll
  for (int qt = 0; qt < 2; ++qt) {
    float inv = 1.0f / l_acc[qt][0];
    int q = q0 + w * 32 + qt * 16 + lr;
    unsigned short* cp = ctx + ((size_t)(b * 2048 + q) * 16 + h) * 64 + lg * 4;
#pragma unroll
    for (int dt = 0; dt < 4; ++dt) {
      f32x4 o = o_acc[qt][dt];
      uint2 u;
      u.x = pk2(o[0] * inv, o[1] * inv);
      u.y = pk2(o[2] * inv, o[3] * inv);
      *(uint2*)(cp + dt * 16) = u;
    }
  }
}

// ---------------------------------------------------------------------------
// Launch pipeline. Workspace layout (72 MB):
//   0: wqt 2MB | 2: wkt | 4: wvt | 6: wot          (bf16 W^T [N,K])
//   8: qh 16MB [B,H,S,D] | 24: kh | 40: vt [B,H,D,S] | 56: ctx [B,S,H,D]
// fp32->bf16 cast of Q/K/V is fused into gemm_qkv's A-staging (no scratch).
// ---------------------------------------------------------------------------
extern "C" void kernel_launch(void* const* d_in, const int* in_sizes, int n_in,
                              void* d_out, int out_size, void* d_ws, size_t ws_size,
                              hipStream_t stream) {
  (void)in_sizes; (void)n_in; (void)out_size; (void)ws_size;
  const float* Q = (const float*)d_in[0];
  const float* K = (const float*)d_in[1];
  const float* V = (const float*)d_in[2];
  const float* mask = (const float*)d_in[3];
  const float* Wq = (const float*)d_in[4];
  const float* bq = (const float*)d_in[5];
  const float* Wk = (const float*)d_in[6];
  const float* bk = (const float*)d_in[7];
  const float* Wv = (const float*)d_in[8];
  const float* bv = (const float*)d_in[9];
  const float* Wo = (const float*)d_in[10];
  const float* bo = (const float*)d_in[11];

  char* ws = (char*)d_ws;
  unsigned short* wqt = (unsigned short*)(ws + (size_t)0);
  unsigned short* wkt = (unsigned short*)(ws + ((size_t)2 << 20));
  unsigned short* wvt = (unsigned short*)(ws + ((size_t)4 << 20));
  unsigned short* wot = (unsigned short*)(ws + ((size_t)6 << 20));
  unsigned short* qhb = (unsigned short*)(ws + ((size_t)8 << 20));
  unsigned short* khb = (unsigned short*)(ws + ((size_t)24 << 20));
  unsigned short* vtb = (unsigned short*)(ws + ((size_t)40 << 20));
  unsigned short* ctx = (unsigned short*)(ws + ((size_t)56 << 20));

  wtrans<<<dim3(32, 32, 4), dim3(32, 8), 0, stream>>>(Wq, Wk, Wv, Wo, wqt, wkt, wvt, wot);

  const float qscale = 0.18033688011112042f;  // log2(e)/8, folded into Q projection

  gemm_qkv<<<dim3(8, 64, 3), dim3(256), 0, stream>>>(Q, K, V, wqt, wkt, wvt, bq, bk, bv,
                                                     qhb, khb, vtb, qscale);

  flash_attn<<<dim3(1024), dim3(256), 0, stream>>>(qhb, khb, vtb, mask, ctx);

  gemm_out<<<dim3(8, 64), dim3(256), 0, stream>>>(ctx, wot, bo, (float*)d_out);
}

// Round 8
// 368.491 us; speedup vs baseline: 1.0564x; 1.0306x over previous
//
#include <hip/hip_runtime.h>

typedef short s16x8 __attribute__((ext_vector_type(8)));
typedef short s16x4 __attribute__((ext_vector_type(4)));
typedef float f32x4 __attribute__((ext_vector_type(4)));

#define MFMA32(a, b, c) __builtin_amdgcn_mfma_f32_16x16x32_bf16((a), (b), (c), 0, 0, 0)

// async global->LDS DMA, 16B per lane; LDS dest = wave-uniform base + lane*16
__device__ __forceinline__ void stage16(const unsigned short* g, unsigned short* l) {
#if defined(__HIP_DEVICE_COMPILE__)
  __builtin_amdgcn_global_load_lds((const __attribute__((address_space(1))) unsigned int*)g,
                                   (__attribute__((address_space(3))) unsigned int*)l, 16, 0, 0);
#endif
}

// fp32 -> bf16 bits, round-nearest-even
__device__ __forceinline__ unsigned short f2b(float f) {
  unsigned int u = __builtin_bit_cast(unsigned int, f);
  unsigned int r = u + 0x7FFFu + ((u >> 16) & 1u);
  return (unsigned short)(r >> 16);
}
// pack two fp32 into bf16x2 (RNE). Device: 2x round-add + 1x v_perm_b32
// (bytes {2,3} of each rounded value == >>16). Bit-identical to f2b pair.
__device__ __forceinline__ unsigned int pk2(float a, float b) {
#if defined(__HIP_DEVICE_COMPILE__)
  unsigned int ua = __builtin_bit_cast(unsigned int, a);
  unsigned int ub = __builtin_bit_cast(unsigned int, b);
  ua += 0x7FFFu + ((ua >> 16) & 1u);
  ub += 0x7FFFu + ((ub >> 16) & 1u);
  return __builtin_amdgcn_perm(ub, ua, 0x07060302u);  // {ub.b3, ub.b2, ua.b3, ua.b2}
#else
  return (unsigned int)f2b(a) | ((unsigned int)f2b(b) << 16);
#endif
}
__device__ __forceinline__ float fast_exp2(float x) {
#if defined(__HIP_DEVICE_COMPILE__) && __has_builtin(__builtin_amdgcn_exp2f)
  return __builtin_amdgcn_exp2f(x);
#else
  return exp2f(x);
#endif
}

// ---------------------------------------------------------------------------
// Weight transpose + cast: T[n][k] = bf16(W[k][n]), 1024x1024, z selects matrix
// ---------------------------------------------------------------------------
__global__ void wtrans(const float* __restrict__ W0, const float* __restrict__ W1,
                       const float* __restrict__ W2, const float* __restrict__ W3,
                       unsigned short* __restrict__ T0, unsigned short* __restrict__ T1,
                       unsigned short* __restrict__ T2, unsigned short* __restrict__ T3) {
  const float* W;
  unsigned short* T;
  switch (blockIdx.z) {
    case 0: W = W0; T = T0; break;
    case 1: W = W1; T = T1; break;
    case 2: W = W2; T = T2; break;
    default: W = W3; T = T3; break;
  }
  __shared__ float tile[32][33];
  const int n0 = blockIdx.x << 5;
  const int k0 = blockIdx.y << 5;
  const int tx = threadIdx.x;
  const int ty = threadIdx.y;
#pragma unroll
  for (int j = 0; j < 4; ++j)
    tile[ty + 8 * j][tx] = W[(size_t)(k0 + ty + 8 * j) * 1024 + n0 + tx];
  __syncthreads();
#pragma unroll
  for (int j = 0; j < 4; ++j)
    T[(size_t)(n0 + ty + 8 * j) * 1024 + k0 + tx] = f2b(tile[tx][ty + 8 * j]);
}

// ---------------------------------------------------------------------------
// Fused QKV projection GEMM, one dispatch. XCD-AWARE SWIZZLE (T1): hardware
// round-robins linear block id across 8 XCDs; the 8 n-tiles sharing one
// 512KB A-panel (same ty,tz) previously landed on 8 different XCDs, each
// refetching the panel from HBM (measured: FETCH 396MB vs 102MB ideal, 3.8x).
// Remap (bijective on 1536): xcd=lid&7, s=lid>>3, tx=s&7, g=((s>>3)<<3)|xcd,
// ty=g&63, tz=g>>6  ->  all 8 tx of group g satisfy lid%8==g%8 (same XCD,
// consecutive slots), so the A-panel is fetched once into that XCD's L2.
// C[8192,1024] = bf16(A_fp32[8192,1024]) @ Wt[1024,1024]^T + bias.
// A read directly as fp32, converted via pk2, ds_write_b128 into LDS; B via
// global_load_lds. 2-phase pipeline. tz=0,1: bf16 [B,H,S,D]; tz=2: [B,H,D,S].
// ---------------------------------------------------------------------------
__global__ __launch_bounds__(256, 3) void gemm_qkv(
    const float* __restrict__ Qf, const float* __restrict__ Kf, const float* __restrict__ Vf,
    const unsigned short* __restrict__ Wqt, const unsigned short* __restrict__ Wkt,
    const unsigned short* __restrict__ Wvt, const float* __restrict__ bq,
    const float* __restrict__ bk, const float* __restrict__ bv,
    unsigned short* __restrict__ qh, unsigned short* __restrict__ kh,
    unsigned short* __restrict__ vtb, float qscale) {
  const int lid = blockIdx.x + (blockIdx.y << 3) + (blockIdx.z << 9);
  const int xcd = lid & 7;
  const int s = lid >> 3;                 // 0..191
  const int tx = s & 7;                   // n-tile
  const int g = ((s >> 3) << 3) | xcd;    // 0..191, g%8 == xcd
  const int ty = g & 63;                  // m-tile
  const int tz = g >> 6;                  // operand select

  const float* A;
  const unsigned short* Bt;
  const float* bias;
  unsigned short* Cout;
  float oscale = 1.0f;
  int vmode = 0;
  switch (tz) {
    case 0: A = Qf; Bt = Wqt; bias = bq; Cout = qh; oscale = qscale; break;
    case 1: A = Kf; Bt = Wkt; bias = bk; Cout = kh; break;
    default: A = Vf; Bt = Wvt; bias = bv; Cout = vtb; vmode = 1; break;
  }
  __shared__ __align__(16) unsigned short As[2 * 128 * 32];
  __shared__ __align__(16) unsigned short Bs[2 * 128 * 32];
  const int n0 = tx * 128;
  const int m0 = ty * 128;
  const int tid = threadIdx.x;
  const int w = tid >> 6;
  const int lane = tid & 63;
  const int lr = lane & 15;
  const int lg = lane >> 4;
  const int wm = (w >> 1) << 6;
  const int wn = (w & 1) << 6;

  // staging geometry (per wave, halves i=0,1): row = i*64 + w*16 + (lane>>2),
  // 16B segment = lane&3. LDS byte offset within half = lane*16.
  const int srow = w * 16 + (lane >> 2);
  const int sseg = lane & 3;
  const float* Ag0 = A + (size_t)(m0 + srow) * 1024 + sseg * 8;
  const float* Ag1 = A + (size_t)(m0 + 64 + srow) * 1024 + sseg * 8;
  const unsigned short* Bg0 = Bt + (size_t)(n0 + srow) * 1024 + sseg * 8;
  const unsigned short* Bg1 = Bt + (size_t)(n0 + 64 + srow) * 1024 + sseg * 8;
  unsigned short* Bl0 = &Bs[(w * 16) * 32];
  unsigned short* Bl1 = &Bs[(64 + w * 16) * 32];
  // per-lane A ds_write targets (element offsets within a buffer)
  const int aoff0 = (w * 16) * 32 + lane * 8;
  const int aoff1 = (64 + w * 16) * 32 + lane * 8;

  f32x4 acc[4][4];
#pragma unroll
  for (int i = 0; i < 4; ++i)
#pragma unroll
    for (int j = 0; j < 4; ++j) {
      f32x4 z = {0.f, 0.f, 0.f, 0.f};
      acc[i][j] = z;
    }

  // prologue: stage K-step 0 into buffer 0 (A via regs+cvt, B via DMA)
  {
    float4 a0lo = *(const float4*)Ag0;
    float4 a0hi = *(const float4*)(Ag0 + 4);
    float4 a1lo = *(const float4*)Ag1;
    float4 a1hi = *(const float4*)(Ag1 + 4);
    stage16(Bg0, Bl0);
    stage16(Bg1, Bl1);
    uint4 u0, u1;
    u0.x = pk2(a0lo.x, a0lo.y); u0.y = pk2(a0lo.z, a0lo.w);
    u0.z = pk2(a0hi.x, a0hi.y); u0.w = pk2(a0hi.z, a0hi.w);
    u1.x = pk2(a1lo.x, a1lo.y); u1.y = pk2(a1lo.z, a1lo.w);
    u1.z = pk2(a1hi.x, a1hi.y); u1.w = pk2(a1hi.z, a1hi.w);
    *(uint4*)&As[aoff0] = u0;
    *(uint4*)&As[aoff1] = u1;
  }
  asm volatile("s_waitcnt vmcnt(0) lgkmcnt(0)\n\ts_barrier" ::: "memory");

  int cur = 0;
  for (int k0 = 0; k0 < 1024; k0 += 32) {
    const bool next = (k0 + 32) < 1024;
    float4 a0lo, a0hi, a1lo, a1hi;
    if (next) {
      a0lo = *(const float4*)(Ag0 + k0 + 32);
      a0hi = *(const float4*)(Ag0 + k0 + 36);
      a1lo = *(const float4*)(Ag1 + k0 + 32);
      a1hi = *(const float4*)(Ag1 + k0 + 36);
      const int nb = (cur ^ 1) * 4096;
      stage16(Bg0 + k0 + 32, Bl0 + nb);
      stage16(Bg1 + k0 + 32, Bl1 + nb);
    }
    const int cb = cur * 4096;
    s16x8 af[4], bfr[4];
#pragma unroll
    for (int mt = 0; mt < 4; ++mt)
      af[mt] = *(const s16x8*)&As[cb + (wm + mt * 16 + lr) * 32 + lg * 8];
#pragma unroll
    for (int nt = 0; nt < 4; ++nt)
      bfr[nt] = *(const s16x8*)&Bs[cb + (wn + nt * 16 + lr) * 32 + lg * 8];
#pragma unroll
    for (int mt = 0; mt < 4; ++mt)
#pragma unroll
      for (int nt = 0; nt < 4; ++nt)
        acc[mt][nt] = MFMA32(af[mt], bfr[nt], acc[mt][nt]);
    if (next) {
      const int nb = (cur ^ 1) * 4096;
      uint4 u0, u1;
      u0.x = pk2(a0lo.x, a0lo.y); u0.y = pk2(a0lo.z, a0lo.w);
      u0.z = pk2(a0hi.x, a0hi.y); u0.w = pk2(a0hi.z, a0hi.w);
      u1.x = pk2(a1lo.x, a1lo.y); u1.y = pk2(a1lo.z, a1lo.w);
      u1.z = pk2(a1hi.x, a1hi.y); u1.w = pk2(a1hi.z, a1hi.w);
      *(uint4*)&As[nb + aoff0] = u0;
      *(uint4*)&As[nb + aoff1] = u1;
    }
    // B-DMA (untracked by compiler) + A ds_writes must be visible before the
    // next iteration's reads in ALL waves.
    asm volatile("s_waitcnt vmcnt(0) lgkmcnt(0)\n\ts_barrier" ::: "memory");
    cur ^= 1;
  }

  float bcol[4];
#pragma unroll
  for (int nt = 0; nt < 4; ++nt) bcol[nt] = bias[n0 + wn + nt * 16 + lr];

  if (vmode == 0) {
#pragma unroll
    for (int mt = 0; mt < 4; ++mt)
#pragma unroll
      for (int nt = 0; nt < 4; ++nt)
#pragma unroll
        for (int r = 0; r < 4; ++r) {
          float v = (acc[mt][nt][r] + bcol[nt]) * oscale;
          int row = m0 + wm + mt * 16 + lg * 4 + r;  // token (b*2048+s)
          int col = n0 + wn + nt * 16 + lr;          // feature (h*64+d)
          int b = row >> 11, ss = row & 2047, hh = col >> 6, d = col & 63;
          Cout[(((size_t)(b * 16 + hh) * 2048 + ss) << 6) + d] = f2b(v);
        }
  } else {
#pragma unroll
    for (int mt = 0; mt < 4; ++mt)
#pragma unroll
      for (int nt = 0; nt < 4; ++nt)
#pragma unroll
        for (int r = 0; r < 4; ++r) {
          float v = acc[mt][nt][r] + bcol[nt];
          int row = m0 + wm + mt * 16 + lg * 4 + r;
          int col = n0 + wn + nt * 16 + lr;
          int b = row >> 11, ss = row & 2047, hh = col >> 6, d = col & 63;
          Cout[(((size_t)(b * 16 + hh) * 64 + d) << 11) + ss] = f2b(v);
        }
  }
}

// ---------------------------------------------------------------------------
// Output GEMM (Wo): C[8192,1024]fp32 = ctx[8192,1024]bf16 @ Wot^T + bias.
// Same XCD-aware swizzle (bijective on 512): all 8 n-tiles of a ctx-panel
// land on one XCD. 2-phase structure, bf16 A via global_load_lds.
// ---------------------------------------------------------------------------
__global__ __launch_bounds__(256, 3) void gemm_out(const unsigned short* __restrict__ A,
                                                   const unsigned short* __restrict__ Bt,
                                                   const float* __restrict__ bias,
                                                   float* __restrict__ Cout) {
  const int lid = blockIdx.x + (blockIdx.y << 3);
  const int xcd = lid & 7;
  const int s = lid >> 3;                 // 0..63
  const int tx = s & 7;
  const int ty = ((s >> 3) << 3) | xcd;   // 0..63

  __shared__ __align__(16) unsigned short As[2 * 128 * 32];
  __shared__ __align__(16) unsigned short Bs[2 * 128 * 32];
  const int n0 = tx * 128;
  const int m0 = ty * 128;
  const int tid = threadIdx.x;
  const int w = tid >> 6;
  const int lane = tid & 63;
  const int lr = lane & 15;
  const int lg = lane >> 4;
  const int wm = (w >> 1) << 6;
  const int wn = (w & 1) << 6;

  const int srow = w * 16 + (lane >> 2);
  const int sseg = lane & 3;
  const unsigned short* Ag0 = A + (size_t)(m0 + srow) * 1024 + sseg * 8;
  const unsigned short* Ag1 = A + (size_t)(m0 + 64 + srow) * 1024 + sseg * 8;
  const unsigned short* Bg0 = Bt + (size_t)(n0 + srow) * 1024 + sseg * 8;
  const unsigned short* Bg1 = Bt + (size_t)(n0 + 64 + srow) * 1024 + sseg * 8;
  unsigned short* Al0 = &As[(w * 16) * 32];
  unsigned short* Al1 = &As[(64 + w * 16) * 32];
  unsigned short* Bl0 = &Bs[(w * 16) * 32];
  unsigned short* Bl1 = &Bs[(64 + w * 16) * 32];

  f32x4 acc[4][4];
#pragma unroll
  for (int i = 0; i < 4; ++i)
#pragma unroll
    for (int j = 0; j < 4; ++j) {
      f32x4 z = {0.f, 0.f, 0.f, 0.f};
      acc[i][j] = z;
    }

  stage16(Ag0, Al0);
  stage16(Ag1, Al1);
  stage16(Bg0, Bl0);
  stage16(Bg1, Bl1);
  asm volatile("s_waitcnt vmcnt(0)\n\ts_barrier" ::: "memory");

  int cur = 0;
  for (int k0 = 0; k0 < 1024; k0 += 32) {
    if (k0 + 32 < 1024) {
      const int nb = (cur ^ 1) * 4096;
      stage16(Ag0 + k0 + 32, Al0 + nb);
      stage16(Ag1 + k0 + 32, Al1 + nb);
      stage16(Bg0 + k0 + 32, Bl0 + nb);
      stage16(Bg1 + k0 + 32, Bl1 + nb);
    }
    const int cb = cur * 4096;
    s16x8 af[4], bfr[4];
#pragma unroll
    for (int mt = 0; mt < 4; ++mt)
      af[mt] = *(const s16x8*)&As[cb + (wm + mt * 16 + lr) * 32 + lg * 8];
#pragma unroll
    for (int nt = 0; nt < 4; ++nt)
      bfr[nt] = *(const s16x8*)&Bs[cb + (wn + nt * 16 + lr) * 32 + lg * 8];
#pragma unroll
    for (int mt = 0; mt < 4; ++mt)
#pragma unroll
      for (int nt = 0; nt < 4; ++nt)
        acc[mt][nt] = MFMA32(af[mt], bfr[nt], acc[mt][nt]);
    asm volatile("s_waitcnt vmcnt(0)\n\ts_barrier" ::: "memory");
    cur ^= 1;
  }

  float bcol[4];
#pragma unroll
  for (int nt = 0; nt < 4; ++nt) bcol[nt] = bias[n0 + wn + nt * 16 + lr];

#pragma unroll
  for (int mt = 0; mt < 4; ++mt)
#pragma unroll
    for (int nt = 0; nt < 4; ++nt)
#pragma unroll
      for (int r = 0; r < 4; ++r) {
        float v = acc[mt][nt][r] + bcol[nt];
        int row = m0 + wm + mt * 16 + lg * 4 + r;
        int col = n0 + wn + nt * 16 + lr;
        Cout[(size_t)row * 1024 + col] = v;
      }
}

// ---------------------------------------------------------------------------
// Flash attention, transposed-S, double-buffered LDS K/V (T3 2-phase pipeline).
// PV + l-sum on 16x16x32 MFMA (round-4-verified slot-permutation layout).
// ---------------------------------------------------------------------------
__global__ __launch_bounds__(256, 4) void flash_attn(const unsigned short* __restrict__ qh,
                                                     const unsigned short* __restrict__ kh,
                                                     const unsigned short* __restrict__ vt,
                                                     const float* __restrict__ mask,
                                                     unsigned short* __restrict__ ctx) {
  const float c2 = 1.4426950408889634e9f;  // 1e9*log2(e)
  const int id = blockIdx.x;
  const int bh = id & 63;
  const int qtile = id >> 6;
  const int b = bh >> 4;
  const int h = bh & 15;
  const int q0 = qtile << 7;
  const int tid = threadIdx.x;
  const int w = tid >> 6;
  const int lane = tid & 63;
  const int lr = lane & 15;
  const int lg = lane >> 4;

  __shared__ __align__(16) unsigned short Ks[2 * 64 * 64];  // [buf][key][d], swizzled segs
  __shared__ __align__(16) unsigned short Vs[2 * 64 * 64];  // [buf][d][key], swizzled segs

  const unsigned short* qbase = qh + ((size_t)bh * 2048 + q0 + w * 32) * 64;
  const unsigned short* kbase = kh + (size_t)bh * 2048 * 64;
  const unsigned short* vbase = vt + (size_t)bh * 64 * 2048;
  const float* mbase = mask + b * 2048;

  const int rowc = lane >> 3;
  const int gseg = (lane & 7) ^ rowc;
  const unsigned short* kg0 = kbase + (size_t)(w * 16 + rowc) * 64 + gseg * 8;
  const unsigned short* kg1 = kbase + (size_t)(w * 16 + 8 + rowc) * 64 + gseg * 8;
  const unsigned short* vg0 = vbase + (size_t)(w * 16 + rowc) * 2048 + gseg * 8;
  const unsigned short* vg1 = vbase + (size_t)(w * 16 + 8 + rowc) * 2048 + gseg * 8;
  unsigned short* kl0 = &Ks[(w * 16 + 0) * 64];
  unsigned short* kl1 = &Ks[(w * 16 + 8) * 64];
  unsigned short* vl0 = &Vs[(w * 16 + 0) * 64];
  unsigned short* vl1 = &Vs[(w * 16 + 8) * 64];

  s16x8 qf[2][2];
#pragma unroll
  for (int qt = 0; qt < 2; ++qt)
#pragma unroll
    for (int kk = 0; kk < 2; ++kk)
      qf[qt][kk] = *(const s16x8*)(qbase + (qt * 16 + lr) * 64 + kk * 32 + lg * 8);

  const s16x8 ones8 = {(short)0x3F80, (short)0x3F80, (short)0x3F80, (short)0x3F80,
                       (short)0x3F80, (short)0x3F80, (short)0x3F80, (short)0x3F80};

  f32x4 o_acc[2][4];
  f32x4 l_acc[2];
#pragma unroll
  for (int qt = 0; qt < 2; ++qt) {
    f32x4 z = {0.f, 0.f, 0.f, 0.f};
    l_acc[qt] = z;
#pragma unroll
    for (int dt = 0; dt < 4; ++dt) o_acc[qt][dt] = z;
  }

  // prologue: stage tile 0 into buffer 0, drain, sync
  stage16(kg0, kl0);
  stage16(kg1, kl1);
  stage16(vg0, vl0);
  stage16(vg1, vl1);
  asm volatile("s_waitcnt vmcnt(0)\n\ts_barrier" ::: "memory");

  int cur = 0;
  for (int t0 = 0; t0 < 2048; t0 += 64) {
    // issue next tile's DMA into the other buffer (in flight during compute)
    if (t0 + 64 < 2048) {
      const int nb = (cur ^ 1) * 4096;
      stage16(kg0 + (size_t)(t0 + 64) * 64, kl0 + nb);
      stage16(kg1 + (size_t)(t0 + 64) * 64, kl1 + nb);
      stage16(vg0 + (t0 + 64), vl0 + nb);
      stage16(vg1 + (t0 + 64), vl1 + nb);
    }
    float4 mk[4];
#pragma unroll
    for (int kt = 0; kt < 4; ++kt) mk[kt] = *(const float4*)(mbase + t0 + kt * 16 + lg * 4);

    const int cb = cur * 4096;
    const int sw = lr & 7;
    // scores -> exp2 -> packed bf16 pairs.
    // pw[kt][qt][u]: keys kt*16 + lg*4 + {2u, 2u+1}, query = lr
    unsigned int pw[4][2][2];
#pragma unroll
    for (int kt = 0; kt < 4; ++kt) {
      const int krow = kt * 16 + lr;
      s16x8 kf0 = *(const s16x8*)&Ks[cb + krow * 64 + ((lg ^ sw) * 8)];
      s16x8 kf1 = *(const s16x8*)&Ks[cb + krow * 64 + (((4 + lg) ^ sw) * 8)];
      float ml0 = mk[kt].x * c2, ml1 = mk[kt].y * c2;
      float ml2 = mk[kt].z * c2, ml3 = mk[kt].w * c2;
#pragma unroll
      for (int qt = 0; qt < 2; ++qt) {
        f32x4 s = {0.f, 0.f, 0.f, 0.f};
        s = MFMA32(kf0, qf[qt][0], s);
        s = MFMA32(kf1, qf[qt][1], s);
        pw[kt][qt][0] = pk2(fast_exp2(s[0] - ml0), fast_exp2(s[1] - ml1));
        pw[kt][qt][1] = pk2(fast_exp2(s[2] - ml2), fast_exp2(s[3] - ml3));
      }
    }

    // PV + l-sum on MFMA32. Chunk c covers keys 32c..32c+31.
    // B position (lg,j) <-> key 32c + (j>=4)*16 + lg*4 + (j&3); V reads match.
#pragma unroll
    for (int c = 0; c < 2; ++c) {
      s16x8 pb[2];
#pragma unroll
      for (int qt = 0; qt < 2; ++qt) {
        uint4 u;
        u.x = pw[2 * c][qt][0];
        u.y = pw[2 * c][qt][1];
        u.z = pw[2 * c + 1][qt][0];
        u.w = pw[2 * c + 1][qt][1];
        pb[qt] = __builtin_bit_cast(s16x8, u);
        l_acc[qt] = MFMA32(ones8, pb[qt], l_acc[qt]);
      }
      const int plo = ((c << 2) | (lg >> 1)) ^ sw;
      const int phi = ((c << 2) | 2 | (lg >> 1)) ^ sw;
      const int sub = (lg & 1) * 4;
#pragma unroll
      for (int dt = 0; dt < 4; ++dt) {
        const int d = dt * 16 + lr;
        s16x4 vlo = *(const s16x4*)&Vs[cb + d * 64 + plo * 8 + sub];
        s16x4 vhi = *(const s16x4*)&Vs[cb + d * 64 + phi * 8 + sub];
        s16x8 vf = __builtin_shufflevector(vlo, vhi, 0, 1, 2, 3, 4, 5, 6, 7);
#pragma unroll
        for (int qt = 0; qt < 2; ++qt) o_acc[qt][dt] = MFMA32(vf, pb[qt], o_acc[qt][dt]);
      }
    }

    // drain next-tile DMA (covered by compute above) + separate buf reuse
    asm volatile("s_waitcnt vmcnt(0)\n\ts_barrier" ::: "memory");
    cur ^= 1;
  }

#pragma unroll
  for (int qt = 0; qt < 2; ++qt) {
    float inv = 1.0f / l_acc[qt][0];
    int q = q0 + w * 32 + qt * 16 + lr;
    unsigned short* cp = ctx + ((size_t)(b * 2048 + q) * 16 + h) * 64 + lg * 4;
#pragma unroll
    for (int dt = 0; dt < 4; ++dt) {
      f32x4 o = o_acc[qt][dt];
      uint2 u;
      u.x = pk2(o[0] * inv, o[1] * inv);
      u.y = pk2(o[2] * inv, o[3] * inv);
      *(uint2*)(cp + dt * 16) = u;
    }
  }
}

// ---------------------------------------------------------------------------
// Launch pipeline. Workspace layout (72 MB):
//   0: wqt 2MB | 2: wkt | 4: wvt | 6: wot          (bf16 W^T [N,K])
//   8: qh 16MB [B,H,S,D] | 24: kh | 40: vt [B,H,D,S] | 56: ctx [B,S,H,D]
// fp32->bf16 cast of Q/K/V is fused into gemm_qkv's A-staging (no scratch).
// ---------------------------------------------------------------------------
extern "C" void kernel_launch(void* const* d_in, const int* in_sizes, int n_in,
                              void* d_out, int out_size, void* d_ws, size_t ws_size,
                              hipStream_t stream) {
  (void)in_sizes; (void)n_in; (void)out_size; (void)ws_size;
  const float* Q = (const float*)d_in[0];
  const float* K = (const float*)d_in[1];
  const float* V = (const float*)d_in[2];
  const float* mask = (const float*)d_in[3];
  const float* Wq = (const float*)d_in[4];
  const float* bq = (const float*)d_in[5];
  const float* Wk = (const float*)d_in[6];
  const float* bk = (const float*)d_in[7];
  const float* Wv = (const float*)d_in[8];
  const float* bv = (const float*)d_in[9];
  const float* Wo = (const float*)d_in[10];
  const float* bo = (const float*)d_in[11];

  char* ws = (char*)d_ws;
  unsigned short* wqt = (unsigned short*)(ws + (size_t)0);
  unsigned short* wkt = (unsigned short*)(ws + ((size_t)2 << 20));
  unsigned short* wvt = (unsigned short*)(ws + ((size_t)4 << 20));
  unsigned short* wot = (unsigned short*)(ws + ((size_t)6 << 20));
  unsigned short* qhb = (unsigned short*)(ws + ((size_t)8 << 20));
  unsigned short* khb = (unsigned short*)(ws + ((size_t)24 << 20));
  unsigned short* vtb = (unsigned short*)(ws + ((size_t)40 << 20));
  unsigned short* ctx = (unsigned short*)(ws + ((size_t)56 << 20));

  wtrans<<<dim3(32, 32, 4), dim3(32, 8), 0, stream>>>(Wq, Wk, Wv, Wo, wqt, wkt, wvt, wot);

  const float qscale = 0.18033688011112042f;  // log2(e)/8, folded into Q projection

  gemm_qkv<<<dim3(8, 64, 3), dim3(256), 0, stream>>>(Q, K, V, wqt, wkt, wvt, bq, bk, bv,
                                                     qhb, khb, vtb, qscale);

  flash_attn<<<dim3(1024), dim3(256), 0, stream>>>(qhb, khb, vtb, mask, ctx);

  gemm_out<<<dim3(8, 64), dim3(256), 0, stream>>>(ctx, wot, bo, (float*)d_out);
}

// Round 9
// 361.684 us; speedup vs baseline: 1.0763x; 1.0188x over previous
//
#include <hip/hip_runtime.h>

typedef short s16x8 __attribute__((ext_vector_type(8)));
typedef short s16x4 __attribute__((ext_vector_type(4)));
typedef float f32x4 __attribute__((ext_vector_type(4)));

#define MFMA32(a, b, c) __builtin_amdgcn_mfma_f32_16x16x32_bf16((a), (b), (c), 0, 0, 0)

// async global->LDS DMA, 16B per lane; LDS dest = wave-uniform base + lane*16
__device__ __forceinline__ void stage16(const unsigned short* g, unsigned short* l) {
#if defined(__HIP_DEVICE_COMPILE__)
  __builtin_amdgcn_global_load_lds((const __attribute__((address_space(1))) unsigned int*)g,
                                   (__attribute__((address_space(3))) unsigned int*)l, 16, 0, 0);
#endif
}

// fp32 -> bf16 bits, round-nearest-even
__device__ __forceinline__ unsigned short f2b(float f) {
  unsigned int u = __builtin_bit_cast(unsigned int, f);
  unsigned int r = u + 0x7FFFu + ((u >> 16) & 1u);
  return (unsigned short)(r >> 16);
}
// pack two fp32 into bf16x2 (RNE). Device: 2x round-add + 1x v_perm_b32
// (bytes {2,3} of each rounded value == >>16). Bit-identical to f2b pair.
__device__ __forceinline__ unsigned int pk2(float a, float b) {
#if defined(__HIP_DEVICE_COMPILE__)
  unsigned int ua = __builtin_bit_cast(unsigned int, a);
  unsigned int ub = __builtin_bit_cast(unsigned int, b);
  ua += 0x7FFFu + ((ua >> 16) & 1u);
  ub += 0x7FFFu + ((ub >> 16) & 1u);
  return __builtin_amdgcn_perm(ub, ua, 0x07060302u);  // {ub.b3, ub.b2, ua.b3, ua.b2}
#else
  return (unsigned int)f2b(a) | ((unsigned int)f2b(b) << 16);
#endif
}
__device__ __forceinline__ float fast_exp2(float x) {
#if defined(__HIP_DEVICE_COMPILE__) && __has_builtin(__builtin_amdgcn_exp2f)
  return __builtin_amdgcn_exp2f(x);
#else
  return exp2f(x);
#endif
}

// ---------------------------------------------------------------------------
// Weight transpose + cast: T[n][k] = bf16(W[k][n]), 1024x1024, z selects matrix
// ---------------------------------------------------------------------------
__global__ void wtrans(const float* __restrict__ W0, const float* __restrict__ W1,
                       const float* __restrict__ W2, const float* __restrict__ W3,
                       unsigned short* __restrict__ T0, unsigned short* __restrict__ T1,
                       unsigned short* __restrict__ T2, unsigned short* __restrict__ T3) {
  const float* W;
  unsigned short* T;
  switch (blockIdx.z) {
    case 0: W = W0; T = T0; break;
    case 1: W = W1; T = T1; break;
    case 2: W = W2; T = T2; break;
    default: W = W3; T = T3; break;
  }
  __shared__ float tile[32][33];
  const int n0 = blockIdx.x << 5;
  const int k0 = blockIdx.y << 5;
  const int tx = threadIdx.x;
  const int ty = threadIdx.y;
#pragma unroll
  for (int j = 0; j < 4; ++j)
    tile[ty + 8 * j][tx] = W[(size_t)(k0 + ty + 8 * j) * 1024 + n0 + tx];
  __syncthreads();
#pragma unroll
  for (int j = 0; j < 4; ++j)
    T[(size_t)(n0 + ty + 8 * j) * 1024 + k0 + tx] = f2b(tile[tx][ty + 8 * j]);
}

// ---------------------------------------------------------------------------
// Fused QKV projection GEMM, one dispatch, XCD-aware swizzle (kept: FETCH
// 396->76MB verified round 8). THIS ROUND: T4 counted-vmcnt pipeline.
// Triple-buffered LDS (48KB): iter i reads buf[i%3]; issues B-DMA(i+2);
// converts A(i+1) (regs loaded at iter i-1 -> one full iteration of latency
// coverage; its implicit wait also drains the OLDER B(i+1) DMA, in-order
// vmcnt); ds_writes A(i+1); reloads same regs with A(i+2) (no dynamic reg
// indexing); ends with {vmcnt(6) lgkmcnt(0); barrier} - the 6 newest loads
// (B(i+2)+A(i+2)) stay in flight ACROSS the barrier. Never vmcnt(0) in loop.
// ---------------------------------------------------------------------------
__global__ __launch_bounds__(256, 3) void gemm_qkv(
    const float* __restrict__ Qf, const float* __restrict__ Kf, const float* __restrict__ Vf,
    const unsigned short* __restrict__ Wqt, const unsigned short* __restrict__ Wkt,
    const unsigned short* __restrict__ Wvt, const float* __restrict__ bq,
    const float* __restrict__ bk, const float* __restrict__ bv,
    unsigned short* __restrict__ qh, unsigned short* __restrict__ kh,
    unsigned short* __restrict__ vtb, float qscale) {
  const int lid = blockIdx.x + (blockIdx.y << 3) + (blockIdx.z << 9);
  const int xcd = lid & 7;
  const int sl = lid >> 3;                // 0..191
  const int tx = sl & 7;                  // n-tile
  const int g = ((sl >> 3) << 3) | xcd;   // 0..191, g%8 == xcd
  const int ty = g & 63;                  // m-tile
  const int tz = g >> 6;                  // operand select

  const float* A;
  const unsigned short* Bt;
  const float* bias;
  unsigned short* Cout;
  float oscale = 1.0f;
  int vmode = 0;
  switch (tz) {
    case 0: A = Qf; Bt = Wqt; bias = bq; Cout = qh; oscale = qscale; break;
    case 1: A = Kf; Bt = Wkt; bias = bk; Cout = kh; break;
    default: A = Vf; Bt = Wvt; bias = bv; Cout = vtb; vmode = 1; break;
  }
  __shared__ __align__(16) unsigned short As[3 * 128 * 32];
  __shared__ __align__(16) unsigned short Bs[3 * 128 * 32];
  const int n0 = tx * 128;
  const int m0 = ty * 128;
  const int tid = threadIdx.x;
  const int w = tid >> 6;
  const int lane = tid & 63;
  const int lr = lane & 15;
  const int lg = lane >> 4;
  const int wm = (w >> 1) << 6;
  const int wn = (w & 1) << 6;

  // staging geometry (per wave, halves i=0,1): row = i*64 + w*16 + (lane>>2),
  // 16B segment = lane&3.
  const int srow = w * 16 + (lane >> 2);
  const int sseg = lane & 3;
  const float* Ag0 = A + (size_t)(m0 + srow) * 1024 + sseg * 8;
  const float* Ag1 = A + (size_t)(m0 + 64 + srow) * 1024 + sseg * 8;
  const unsigned short* Bg0 = Bt + (size_t)(n0 + srow) * 1024 + sseg * 8;
  const unsigned short* Bg1 = Bt + (size_t)(n0 + 64 + srow) * 1024 + sseg * 8;
  // rotating buffer base pointers
  unsigned short *ab0 = &As[0], *ab1 = &As[4096], *ab2 = &As[8192];
  unsigned short *bb0 = &Bs[0], *bb1 = &Bs[4096], *bb2 = &Bs[8192];
  const int bl0 = (w * 16) * 32;        // wave's B half-0 offset within buffer
  const int bl1 = (64 + w * 16) * 32;   // half-1
  const int aoff0 = (w * 16) * 32 + lane * 8;
  const int aoff1 = (64 + w * 16) * 32 + lane * 8;

  f32x4 acc[4][4];
#pragma unroll
  for (int i = 0; i < 4; ++i)
#pragma unroll
    for (int j = 0; j < 4; ++j) {
      f32x4 z = {0.f, 0.f, 0.f, 0.f};
      acc[i][j] = z;
    }

  float4 pa0lo, pa0hi, pa1lo, pa1hi;  // single named A-reg set (rule #20)

  // prologue: B(0)->bb0, B(1)->bb1; A(0) regs->convert->ds_write ab0;
  // A(1) -> regs (stays in flight / in regs into iter 0).
  stage16(Bg0, bb0 + bl0);
  stage16(Bg1, bb0 + bl1);
  stage16(Bg0 + 32, bb1 + bl0);
  stage16(Bg1 + 32, bb1 + bl1);
  pa0lo = *(const float4*)Ag0;
  pa0hi = *(const float4*)(Ag0 + 4);
  pa1lo = *(const float4*)Ag1;
  pa1hi = *(const float4*)(Ag1 + 4);
  {
    uint4 u0, u1;
    u0.x = pk2(pa0lo.x, pa0lo.y); u0.y = pk2(pa0lo.z, pa0lo.w);
    u0.z = pk2(pa0hi.x, pa0hi.y); u0.w = pk2(pa0hi.z, pa0hi.w);
    u1.x = pk2(pa1lo.x, pa1lo.y); u1.y = pk2(pa1lo.z, pa1lo.w);
    u1.z = pk2(pa1hi.x, pa1hi.y); u1.w = pk2(pa1hi.z, pa1hi.w);
    *(uint4*)&ab0[aoff0] = u0;
    *(uint4*)&ab0[aoff1] = u1;
  }
  pa0lo = *(const float4*)(Ag0 + 32);
  pa0hi = *(const float4*)(Ag0 + 36);
  pa1lo = *(const float4*)(Ag1 + 32);
  pa1hi = *(const float4*)(Ag1 + 36);
  asm volatile("s_waitcnt lgkmcnt(0)\n\ts_barrier" ::: "memory");

  for (int i = 0; i < 32; ++i) {
    const int k2 = (i + 2) * 32;
    if (i + 2 < 32) {  // issue B(i+2) DMA into bb2
      stage16(Bg0 + k2, bb2 + bl0);
      stage16(Bg1 + k2, bb2 + bl1);
    }
    // compute on buf i (ab0/bb0)
    s16x8 af[4], bfr[4];
#pragma unroll
    for (int mt = 0; mt < 4; ++mt)
      af[mt] = *(const s16x8*)&ab0[(wm + mt * 16 + lr) * 32 + lg * 8];
#pragma unroll
    for (int nt = 0; nt < 4; ++nt)
      bfr[nt] = *(const s16x8*)&bb0[(wn + nt * 16 + lr) * 32 + lg * 8];
#pragma unroll
    for (int mt = 0; mt < 4; ++mt)
#pragma unroll
      for (int nt = 0; nt < 4; ++nt)
        acc[mt][nt] = MFMA32(af[mt], bfr[nt], acc[mt][nt]);
    if (i + 1 < 32) {  // convert A(i+1) (regs from iter i-1), write into ab1
      uint4 u0, u1;
      u0.x = pk2(pa0lo.x, pa0lo.y); u0.y = pk2(pa0lo.z, pa0lo.w);
      u0.z = pk2(pa0hi.x, pa0hi.y); u0.w = pk2(pa0hi.z, pa0hi.w);
      u1.x = pk2(pa1lo.x, pa1lo.y); u1.y = pk2(pa1lo.z, pa1lo.w);
      u1.z = pk2(pa1hi.x, pa1hi.y); u1.w = pk2(pa1hi.z, pa1hi.w);
      *(uint4*)&ab1[aoff0] = u0;
      *(uint4*)&ab1[aoff1] = u1;
    }
    if (i + 2 < 32) {  // reload regs with A(i+2) (WAR on pa* keeps order)
      pa0lo = *(const float4*)(Ag0 + k2);
      pa0hi = *(const float4*)(Ag0 + k2 + 4);
      pa1lo = *(const float4*)(Ag1 + k2);
      pa1hi = *(const float4*)(Ag1 + k2 + 4);
    }
    // keep the 6 newest loads (B(i+2)+A(i+2)) in flight across the barrier;
    // everything older (incl. B(i+1) needed next iter) is drained.
    asm volatile("s_waitcnt vmcnt(6) lgkmcnt(0)\n\ts_barrier" ::: "memory");
    // rotate buffers
    unsigned short* t;
    t = ab0; ab0 = ab1; ab1 = ab2; ab2 = t;
    t = bb0; bb0 = bb1; bb1 = bb2; bb2 = t;
  }

  float bcol[4];
#pragma unroll
  for (int nt = 0; nt < 4; ++nt) bcol[nt] = bias[n0 + wn + nt * 16 + lr];

  if (vmode == 0) {
#pragma unroll
    for (int mt = 0; mt < 4; ++mt)
#pragma unroll
      for (int nt = 0; nt < 4; ++nt)
#pragma unroll
        for (int r = 0; r < 4; ++r) {
          float v = (acc[mt][nt][r] + bcol[nt]) * oscale;
          int row = m0 + wm + mt * 16 + lg * 4 + r;  // token (b*2048+s)
          int col = n0 + wn + nt * 16 + lr;          // feature (h*64+d)
          int b = row >> 11, ss = row & 2047, hh = col >> 6, d = col & 63;
          Cout[(((size_t)(b * 16 + hh) * 2048 + ss) << 6) + d] = f2b(v);
        }
  } else {
#pragma unroll
    for (int mt = 0; mt < 4; ++mt)
#pragma unroll
      for (int nt = 0; nt < 4; ++nt)
#pragma unroll
        for (int r = 0; r < 4; ++r) {
          float v = acc[mt][nt][r] + bcol[nt];
          int row = m0 + wm + mt * 16 + lg * 4 + r;
          int col = n0 + wn + nt * 16 + lr;
          int b = row >> 11, ss = row & 2047, hh = col >> 6, d = col & 63;
          Cout[(((size_t)(b * 16 + hh) * 64 + d) << 11) + ss] = f2b(v);
        }
  }
}

// ---------------------------------------------------------------------------
// Output GEMM (Wo): C[8192,1024]fp32 = ctx[8192,1024]bf16 @ Wot^T + bias.
// XCD swizzle kept. T4 counted-vmcnt triple-buffer, all-DMA staging:
// iter i issues DMA(i+2), computes buf[i%3], ends {vmcnt(4); barrier} —
// DMA(i+1) drained (needed next iter), DMA(i+2) stays in flight.
// ---------------------------------------------------------------------------
__global__ __launch_bounds__(256, 3) void gemm_out(const unsigned short* __restrict__ A,
                                                   const unsigned short* __restrict__ Bt,
                                                   const float* __restrict__ bias,
                                                   float* __restrict__ Cout) {
  const int lid = blockIdx.x + (blockIdx.y << 3);
  const int xcd = lid & 7;
  const int sl = lid >> 3;                // 0..63
  const int tx = sl & 7;
  const int ty = ((sl >> 3) << 3) | xcd;  // 0..63

  __shared__ __align__(16) unsigned short As[3 * 128 * 32];
  __shared__ __align__(16) unsigned short Bs[3 * 128 * 32];
  const int n0 = tx * 128;
  const int m0 = ty * 128;
  const int tid = threadIdx.x;
  const int w = tid >> 6;
  const int lane = tid & 63;
  const int lr = lane & 15;
  const int lg = lane >> 4;
  const int wm = (w >> 1) << 6;
  const int wn = (w & 1) << 6;

  const int srow = w * 16 + (lane >> 2);
  const int sseg = lane & 3;
  const unsigned short* Ag0 = A + (size_t)(m0 + srow) * 1024 + sseg * 8;
  const unsigned short* Ag1 = A + (size_t)(m0 + 64 + srow) * 1024 + sseg * 8;
  const unsigned short* Bg0 = Bt + (size_t)(n0 + srow) * 1024 + sseg * 8;
  const unsigned short* Bg1 = Bt + (size_t)(n0 + 64 + srow) * 1024 + sseg * 8;
  unsigned short *ab0 = &As[0], *ab1 = &As[4096], *ab2 = &As[8192];
  unsigned short *bb0 = &Bs[0], *bb1 = &Bs[4096], *bb2 = &Bs[8192];
  const int hl0 = (w * 16) * 32;
  const int hl1 = (64 + w * 16) * 32;

  f32x4 acc[4][4];
#pragma unroll
  for (int i = 0; i < 4; ++i)
#pragma unroll
    for (int j = 0; j < 4; ++j) {
      f32x4 z = {0.f, 0.f, 0.f, 0.f};
      acc[i][j] = z;
    }

  // prologue: DMA(0)->buf0, DMA(1)->buf1; wait DMA(0) (vmcnt(4): DMA(1) flies)
  stage16(Ag0, ab0 + hl0);
  stage16(Ag1, ab0 + hl1);
  stage16(Bg0, bb0 + hl0);
  stage16(Bg1, bb0 + hl1);
  stage16(Ag0 + 32, ab1 + hl0);
  stage16(Ag1 + 32, ab1 + hl1);
  stage16(Bg0 + 32, bb1 + hl0);
  stage16(Bg1 + 32, bb1 + hl1);
  asm volatile("s_waitcnt vmcnt(4)\n\ts_barrier" ::: "memory");

  for (int i = 0; i < 32; ++i) {
    const int k2 = (i + 2) * 32;
    if (i + 2 < 32) {
      stage16(Ag0 + k2, ab2 + hl0);
      stage16(Ag1 + k2, ab2 + hl1);
      stage16(Bg0 + k2, bb2 + hl0);
      stage16(Bg1 + k2, bb2 + hl1);
    }
    s16x8 af[4], bfr[4];
#pragma unroll
    for (int mt = 0; mt < 4; ++mt)
      af[mt] = *(const s16x8*)&ab0[(wm + mt * 16 + lr) * 32 + lg * 8];
#pragma unroll
    for (int nt = 0; nt < 4; ++nt)
      bfr[nt] = *(const s16x8*)&bb0[(wn + nt * 16 + lr) * 32 + lg * 8];
#pragma unroll
    for (int mt = 0; mt < 4; ++mt)
#pragma unroll
      for (int nt = 0; nt < 4; ++nt)
        acc[mt][nt] = MFMA32(af[mt], bfr[nt], acc[mt][nt]);
    // DMA(i+1) (older) drained for next iter; DMA(i+2) stays in flight.
    asm volatile("s_waitcnt vmcnt(4)\n\ts_barrier" ::: "memory");
    unsigned short* t;
    t = ab0; ab0 = ab1; ab1 = ab2; ab2 = t;
    t = bb0; bb0 = bb1; bb1 = bb2; bb2 = t;
  }

  float bcol[4];
#pragma unroll
  for (int nt = 0; nt < 4; ++nt) bcol[nt] = bias[n0 + wn + nt * 16 + lr];

#pragma unroll
  for (int mt = 0; mt < 4; ++mt)
#pragma unroll
    for (int nt = 0; nt < 4; ++nt)
#pragma unroll
      for (int r = 0; r < 4; ++r) {
        float v = acc[mt][nt][r] + bcol[nt];
        int row = m0 + wm + mt * 16 + lg * 4 + r;
        int col = n0 + wn + nt * 16 + lr;
        Cout[(size_t)row * 1024 + col] = v;
      }
}

// ---------------------------------------------------------------------------
// Flash attention, transposed-S, double-buffered LDS K/V (T3 2-phase pipeline).
// PV + l-sum on 16x16x32 MFMA (round-4-verified slot-permutation layout).
// UNCHANGED (control).
// ---------------------------------------------------------------------------
__global__ __launch_bounds__(256, 4) void flash_attn(const unsigned short* __restrict__ qh,
                                                     const unsigned short* __restrict__ kh,
                                                     const unsigned short* __restrict__ vt,
                                                     const float* __restrict__ mask,
                                                     unsigned short* __restrict__ ctx) {
  const float c2 = 1.4426950408889634e9f;  // 1e9*log2(e)
  const int id = blockIdx.x;
  const int bh = id & 63;
  const int qtile = id >> 6;
  const int b = bh >> 4;
  const int h = bh & 15;
  const int q0 = qtile << 7;
  const int tid = threadIdx.x;
  const int w = tid >> 6;
  const int lane = tid & 63;
  const int lr = lane & 15;
  const int lg = lane >> 4;

  __shared__ __align__(16) unsigned short Ks[2 * 64 * 64];  // [buf][key][d], swizzled segs
  __shared__ __align__(16) unsigned short Vs[2 * 64 * 64];  // [buf][d][key], swizzled segs

  const unsigned short* qbase = qh + ((size_t)bh * 2048 + q0 + w * 32) * 64;
  const unsigned short* kbase = kh + (size_t)bh * 2048 * 64;
  const unsigned short* vbase = vt + (size_t)bh * 64 * 2048;
  const float* mbase = mask + b * 2048;

  const int rowc = lane >> 3;
  const int gseg = (lane & 7) ^ rowc;
  const unsigned short* kg0 = kbase + (size_t)(w * 16 + rowc) * 64 + gseg * 8;
  const unsigned short* kg1 = kbase + (size_t)(w * 16 + 8 + rowc) * 64 + gseg * 8;
  const unsigned short* vg0 = vbase + (size_t)(w * 16 + rowc) * 2048 + gseg * 8;
  const unsigned short* vg1 = vbase + (size_t)(w * 16 + 8 + rowc) * 2048 + gseg * 8;
  unsigned short* kl0 = &Ks[(w * 16 + 0) * 64];
  unsigned short* kl1 = &Ks[(w * 16 + 8) * 64];
  unsigned short* vl0 = &Vs[(w * 16 + 0) * 64];
  unsigned short* vl1 = &Vs[(w * 16 + 8) * 64];

  s16x8 qf[2][2];
#pragma unroll
  for (int qt = 0; qt < 2; ++qt)
#pragma unroll
    for (int kk = 0; kk < 2; ++kk)
      qf[qt][kk] = *(const s16x8*)(qbase + (qt * 16 + lr) * 64 + kk * 32 + lg * 8);

  const s16x8 ones8 = {(short)0x3F80, (short)0x3F80, (short)0x3F80, (short)0x3F80,
                       (short)0x3F80, (short)0x3F80, (short)0x3F80, (short)0x3F80};

  f32x4 o_acc[2][4];
  f32x4 l_acc[2];
#pragma unroll
  for (int qt = 0; qt < 2; ++qt) {
    f32x4 z = {0.f, 0.f, 0.f, 0.f};
    l_acc[qt] = z;
#pragma unroll
    for (int dt = 0; dt < 4; ++dt) o_acc[qt][dt] = z;
  }

  // prologue: stage tile 0 into buffer 0, drain, sync
  stage16(kg0, kl0);
  stage16(kg1, kl1);
  stage16(vg0, vl0);
  stage16(vg1, vl1);
  asm volatile("s_waitcnt vmcnt(0)\n\ts_barrier" ::: "memory");

  int cur = 0;
  for (int t0 = 0; t0 < 2048; t0 += 64) {
    // issue next tile's DMA into the other buffer (in flight during compute)
    if (t0 + 64 < 2048) {
      const int nb = (cur ^ 1) * 4096;
      stage16(kg0 + (size_t)(t0 + 64) * 64, kl0 + nb);
      stage16(kg1 + (size_t)(t0 + 64) * 64, kl1 + nb);
      stage16(vg0 + (t0 + 64), vl0 + nb);
      stage16(vg1 + (t0 + 64), vl1 + nb);
    }
    float4 mk[4];
#pragma unroll
    for (int kt = 0; kt < 4; ++kt) mk[kt] = *(const float4*)(mbase + t0 + kt * 16 + lg * 4);

    const int cb = cur * 4096;
    const int sw = lr & 7;
    // scores -> exp2 -> packed bf16 pairs.
    // pw[kt][qt][u]: keys kt*16 + lg*4 + {2u, 2u+1}, query = lr
    unsigned int pw[4][2][2];
#pragma unroll
    for (int kt = 0; kt < 4; ++kt) {
      const int krow = kt * 16 + lr;
      s16x8 kf0 = *(const s16x8*)&Ks[cb + krow * 64 + ((lg ^ sw) * 8)];
      s16x8 kf1 = *(const s16x8*)&Ks[cb + krow * 64 + (((4 + lg) ^ sw) * 8)];
      float ml0 = mk[kt].x * c2, ml1 = mk[kt].y * c2;
      float ml2 = mk[kt].z * c2, ml3 = mk[kt].w * c2;
#pragma unroll
      for (int qt = 0; qt < 2; ++qt) {
        f32x4 s = {0.f, 0.f, 0.f, 0.f};
        s = MFMA32(kf0, qf[qt][0], s);
        s = MFMA32(kf1, qf[qt][1], s);
        pw[kt][qt][0] = pk2(fast_exp2(s[0] - ml0), fast_exp2(s[1] - ml1));
        pw[kt][qt][1] = pk2(fast_exp2(s[2] - ml2), fast_exp2(s[3] - ml3));
      }
    }

    // PV + l-sum on MFMA32. Chunk c covers keys 32c..32c+31.
    // B position (lg,j) <-> key 32c + (j>=4)*16 + lg*4 + (j&3); V reads match.
#pragma unroll
    for (int c = 0; c < 2; ++c) {
      s16x8 pb[2];
#pragma unroll
      for (int qt = 0; qt < 2; ++qt) {
        uint4 u;
        u.x = pw[2 * c][qt][0];
        u.y = pw[2 * c][qt][1];
        u.z = pw[2 * c + 1][qt][0];
        u.w = pw[2 * c + 1][qt][1];
        pb[qt] = __builtin_bit_cast(s16x8, u);
        l_acc[qt] = MFMA32(ones8, pb[qt], l_acc[qt]);
      }
      const int plo = ((c << 2) | (lg >> 1)) ^ sw;
      const int phi = ((c << 2) | 2 | (lg >> 1)) ^ sw;
      const int sub = (lg & 1) * 4;
#pragma unroll
      for (int dt = 0; dt < 4; ++dt) {
        const int d = dt * 16 + lr;
        s16x4 vlo = *(const s16x4*)&Vs[cb + d * 64 + plo * 8 + sub];
        s16x4 vhi = *(const s16x4*)&Vs[cb + d * 64 + phi * 8 + sub];
        s16x8 vf = __builtin_shufflevector(vlo, vhi, 0, 1, 2, 3, 4, 5, 6, 7);
#pragma unroll
        for (int qt = 0; qt < 2; ++qt) o_acc[qt][dt] = MFMA32(vf, pb[qt], o_acc[qt][dt]);
      }
    }

    // drain next-tile DMA (covered by compute above) + separate buf reuse
    asm volatile("s_waitcnt vmcnt(0)\n\ts_barrier" ::: "memory");
    cur ^= 1;
  }

#pragma unroll
  for (int qt = 0; qt < 2; ++qt) {
    float inv = 1.0f / l_acc[qt][0];
    int q = q0 + w * 32 + qt * 16 + lr;
    unsigned short* cp = ctx + ((size_t)(b * 2048 + q) * 16 + h) * 64 + lg * 4;
#pragma unroll
    for (int dt = 0; dt < 4; ++dt) {
      f32x4 o = o_acc[qt][dt];
      uint2 u;
      u.x = pk2(o[0] * inv, o[1] * inv);
      u.y = pk2(o[2] * inv, o[3] * inv);
      *(uint2*)(cp + dt * 16) = u;
    }
  }
}

// ---------------------------------------------------------------------------
// Launch pipeline. Workspace layout (72 MB):
//   0: wqt 2MB | 2: wkt | 4: wvt | 6: wot          (bf16 W^T [N,K])
//   8: qh 16MB [B,H,S,D] | 24: kh | 40: vt [B,H,D,S] | 56: ctx [B,S,H,D]
// fp32->bf16 cast of Q/K/V is fused into gemm_qkv's A-staging (no scratch).
// ---------------------------------------------------------------------------
extern "C" void kernel_launch(void* const* d_in, const int* in_sizes, int n_in,
                              void* d_out, int out_size, void* d_ws, size_t ws_size,
                              hipStream_t stream) {
  (void)in_sizes; (void)n_in; (void)out_size; (void)ws_size;
  const float* Q = (const float*)d_in[0];
  const float* K = (const float*)d_in[1];
  const float* V = (const float*)d_in[2];
  const float* mask = (const float*)d_in[3];
  const float* Wq = (const float*)d_in[4];
  const float* bq = (const float*)d_in[5];
  const float* Wk = (const float*)d_in[6];
  const float* bk = (const float*)d_in[7];
  const float* Wv = (const float*)d_in[8];
  const float* bv = (const float*)d_in[9];
  const float* Wo = (const float*)d_in[10];
  const float* bo = (const float*)d_in[11];

  char* ws = (char*)d_ws;
  unsigned short* wqt = (unsigned short*)(ws + (size_t)0);
  unsigned short* wkt = (unsigned short*)(ws + ((size_t)2 << 20));
  unsigned short* wvt = (unsigned short*)(ws + ((size_t)4 << 20));
  unsigned short* wot = (unsigned short*)(ws + ((size_t)6 << 20));
  unsigned short* qhb = (unsigned short*)(ws + ((size_t)8 << 20));
  unsigned short* khb = (unsigned short*)(ws + ((size_t)24 << 20));
  unsigned short* vtb = (unsigned short*)(ws + ((size_t)40 << 20));
  unsigned short* ctx = (unsigned short*)(ws + ((size_t)56 << 20));

  wtrans<<<dim3(32, 32, 4), dim3(32, 8), 0, stream>>>(Wq, Wk, Wv, Wo, wqt, wkt, wvt, wot);

  const float qscale = 0.18033688011112042f;  // log2(e)/8, folded into Q projection

  gemm_qkv<<<dim3(8, 64, 3), dim3(256), 0, stream>>>(Q, K, V, wqt, wkt, wvt, bq, bk, bv,
                                                     qhb, khb, vtb, qscale);

  flash_attn<<<dim3(1024), dim3(256), 0, stream>>>(qhb, khb, vtb, mask, ctx);

  gemm_out<<<dim3(8, 64), dim3(256), 0, stream>>>(ctx, wot, bo, (float*)d_out);
}

// Round 10
// 348.227 us; speedup vs baseline: 1.1179x; 1.0386x over previous
//
#include <hip/hip_runtime.h>

typedef short s16x8 __attribute__((ext_vector_type(8)));
typedef short s16x4 __attribute__((ext_vector_type(4)));
typedef float f32x4 __attribute__((ext_vector_type(4)));

#define MFMA32(a, b, c) __builtin_amdgcn_mfma_f32_16x16x32_bf16((a), (b), (c), 0, 0, 0)

// async global->LDS DMA, 16B per lane; LDS dest = wave-uniform base + lane*16
__device__ __forceinline__ void stage16(const unsigned short* g, unsigned short* l) {
#if defined(__HIP_DEVICE_COMPILE__)
  __builtin_amdgcn_global_load_lds((const __attribute__((address_space(1))) unsigned int*)g,
                                   (__attribute__((address_space(3))) unsigned int*)l, 16, 0, 0);
#endif
}

// fp32 -> bf16 bits, round-nearest-even
__device__ __forceinline__ unsigned short f2b(float f) {
  unsigned int u = __builtin_bit_cast(unsigned int, f);
  unsigned int r = u + 0x7FFFu + ((u >> 16) & 1u);
  return (unsigned short)(r >> 16);
}
// pack two fp32 into bf16x2 (RNE). Device: 2x round-add + 1x v_perm_b32
// (bytes {2,3} of each rounded value == >>16). Bit-identical to f2b pair.
__device__ __forceinline__ unsigned int pk2(float a, float b) {
#if defined(__HIP_DEVICE_COMPILE__)
  unsigned int ua = __builtin_bit_cast(unsigned int, a);
  unsigned int ub = __builtin_bit_cast(unsigned int, b);
  ua += 0x7FFFu + ((ua >> 16) & 1u);
  ub += 0x7FFFu + ((ub >> 16) & 1u);
  return __builtin_amdgcn_perm(ub, ua, 0x07060302u);  // {ub.b3, ub.b2, ua.b3, ua.b2}
#else
  return (unsigned int)f2b(a) | ((unsigned int)f2b(b) << 16);
#endif
}
__device__ __forceinline__ float fast_exp2(float x) {
#if defined(__HIP_DEVICE_COMPILE__) && __has_builtin(__builtin_amdgcn_exp2f)
  return __builtin_amdgcn_exp2f(x);
#else
  return exp2f(x);
#endif
}

// ---------------------------------------------------------------------------
// Weight transpose + cast: T[n][k] = bf16(W[k][n]), 1024x1024, z selects matrix
// ---------------------------------------------------------------------------
__global__ void wtrans(const float* __restrict__ W0, const float* __restrict__ W1,
                       const float* __restrict__ W2, const float* __restrict__ W3,
                       unsigned short* __restrict__ T0, unsigned short* __restrict__ T1,
                       unsigned short* __restrict__ T2, unsigned short* __restrict__ T3) {
  const float* W;
  unsigned short* T;
  switch (blockIdx.z) {
    case 0: W = W0; T = T0; break;
    case 1: W = W1; T = T1; break;
    case 2: W = W2; T = T2; break;
    default: W = W3; T = T3; break;
  }
  __shared__ float tile[32][33];
  const int n0 = blockIdx.x << 5;
  const int k0 = blockIdx.y << 5;
  const int tx = threadIdx.x;
  const int ty = threadIdx.y;
#pragma unroll
  for (int j = 0; j < 4; ++j)
    tile[ty + 8 * j][tx] = W[(size_t)(k0 + ty + 8 * j) * 1024 + n0 + tx];
  __syncthreads();
#pragma unroll
  for (int j = 0; j < 4; ++j)
    T[(size_t)(n0 + ty + 8 * j) * 1024 + k0 + tx] = f2b(tile[tx][ty + 8 * j]);
}

// ---------------------------------------------------------------------------
// Fused QKV projection GEMM, XCD-aware swizzle (FETCH 396->76MB, round 8).
// THIS ROUND: A-path pipeline depth 2. A is fp32 + HBM-miss on every load;
// rounds 6/9 left its reg->convert path at depth 1, so the per-iter period
// was bound by contended HBM latency (~3470 cyc/iter measured). Parity-
// unrolled loop with TWO named A-register sets (E/O): at any time A(i+2)
// AND A(i+3) are in flight. End-of-iter wait = vmcnt(10) (those 10 newest
// VMEM ops stay in flight across the barrier; B(i+1) is provably >=11th-
// newest for i<=27); tail iters 28..31 use vmcnt(0) as the census shrinks.
// Triple-buffered LDS (48KB, 3 blocks/CU). Never vmcnt(0) in the hot loop.
// ---------------------------------------------------------------------------
#define QKV_STEP(I, R0LO, R0HI, R1LO, R1HI, VMW)                              \
  {                                                                           \
    if ((I) + 2 < 32) {                                                       \
      stage16(Bg0 + ((I) + 2) * 32, bb2 + bl0);                               \
      stage16(Bg1 + ((I) + 2) * 32, bb2 + bl1);                               \
    }                                                                         \
    s16x8 af[4], bfr[4];                                                      \
    _Pragma("unroll")                                                         \
    for (int mt = 0; mt < 4; ++mt)                                            \
      af[mt] = *(const s16x8*)&ab0[(wm + mt * 16 + lr) * 32 + lg * 8];        \
    _Pragma("unroll")                                                         \
    for (int nt = 0; nt < 4; ++nt)                                            \
      bfr[nt] = *(const s16x8*)&bb0[(wn + nt * 16 + lr) * 32 + lg * 8];       \
    _Pragma("unroll")                                                         \
    for (int mt = 0; mt < 4; ++mt) {                                          \
      _Pragma("unroll")                                                       \
      for (int nt = 0; nt < 4; ++nt)                                          \
        acc[mt][nt] = MFMA32(af[mt], bfr[nt], acc[mt][nt]);                   \
    }                                                                         \
    if ((I) + 1 < 32) {                                                       \
      uint4 u0, u1;                                                           \
      u0.x = pk2(R0LO.x, R0LO.y); u0.y = pk2(R0LO.z, R0LO.w);                 \
      u0.z = pk2(R0HI.x, R0HI.y); u0.w = pk2(R0HI.z, R0HI.w);                 \
      u1.x = pk2(R1LO.x, R1LO.y); u1.y = pk2(R1LO.z, R1LO.w);                 \
      u1.z = pk2(R1HI.x, R1HI.y); u1.w = pk2(R1HI.z, R1HI.w);                 \
      *(uint4*)&ab1[aoff0] = u0;                                              \
      *(uint4*)&ab1[aoff1] = u1;                                              \
    }                                                                         \
    if ((I) + 3 < 32) {                                                       \
      R0LO = *(const float4*)(Ag0 + ((I) + 3) * 32);                          \
      R0HI = *(const float4*)(Ag0 + ((I) + 3) * 32 + 4);                      \
      R1LO = *(const float4*)(Ag1 + ((I) + 3) * 32);                          \
      R1HI = *(const float4*)(Ag1 + ((I) + 3) * 32 + 4);                      \
    }                                                                         \
    asm volatile("s_waitcnt vmcnt(" #VMW ") lgkmcnt(0)\n\ts_barrier" ::: "memory"); \
    {                                                                         \
      unsigned short* t_;                                                     \
      t_ = ab0; ab0 = ab1; ab1 = ab2; ab2 = t_;                               \
      t_ = bb0; bb0 = bb1; bb1 = bb2; bb2 = t_;                               \
    }                                                                         \
  }

__global__ __launch_bounds__(256, 3) void gemm_qkv(
    const float* __restrict__ Qf, const float* __restrict__ Kf, const float* __restrict__ Vf,
    const unsigned short* __restrict__ Wqt, const unsigned short* __restrict__ Wkt,
    const unsigned short* __restrict__ Wvt, const float* __restrict__ bq,
    const float* __restrict__ bk, const float* __restrict__ bv,
    unsigned short* __restrict__ qh, unsigned short* __restrict__ kh,
    unsigned short* __restrict__ vtb, float qscale) {
  const int lid = blockIdx.x + (blockIdx.y << 3) + (blockIdx.z << 9);
  const int xcd = lid & 7;
  const int sl = lid >> 3;                // 0..191
  const int tx = sl & 7;                  // n-tile
  const int g = ((sl >> 3) << 3) | xcd;   // 0..191, g%8 == xcd
  const int ty = g & 63;                  // m-tile
  const int tz = g >> 6;                  // operand select

  const float* A;
  const unsigned short* Bt;
  const float* bias;
  unsigned short* Cout;
  float oscale = 1.0f;
  int vmode = 0;
  switch (tz) {
    case 0: A = Qf; Bt = Wqt; bias = bq; Cout = qh; oscale = qscale; break;
    case 1: A = Kf; Bt = Wkt; bias = bk; Cout = kh; break;
    default: A = Vf; Bt = Wvt; bias = bv; Cout = vtb; vmode = 1; break;
  }
  __shared__ __align__(16) unsigned short As[3 * 128 * 32];
  __shared__ __align__(16) unsigned short Bs[3 * 128 * 32];
  const int n0 = tx * 128;
  const int m0 = ty * 128;
  const int tid = threadIdx.x;
  const int w = tid >> 6;
  const int lane = tid & 63;
  const int lr = lane & 15;
  const int lg = lane >> 4;
  const int wm = (w >> 1) << 6;
  const int wn = (w & 1) << 6;

  const int srow = w * 16 + (lane >> 2);
  const int sseg = lane & 3;
  const float* Ag0 = A + (size_t)(m0 + srow) * 1024 + sseg * 8;
  const float* Ag1 = A + (size_t)(m0 + 64 + srow) * 1024 + sseg * 8;
  const unsigned short* Bg0 = Bt + (size_t)(n0 + srow) * 1024 + sseg * 8;
  const unsigned short* Bg1 = Bt + (size_t)(n0 + 64 + srow) * 1024 + sseg * 8;
  unsigned short *ab0 = &As[0], *ab1 = &As[4096], *ab2 = &As[8192];
  unsigned short *bb0 = &Bs[0], *bb1 = &Bs[4096], *bb2 = &Bs[8192];
  const int bl0 = (w * 16) * 32;
  const int bl1 = (64 + w * 16) * 32;
  const int aoff0 = (w * 16) * 32 + lane * 8;
  const int aoff1 = (64 + w * 16) * 32 + lane * 8;

  f32x4 acc[4][4];
#pragma unroll
  for (int i = 0; i < 4; ++i)
#pragma unroll
    for (int j = 0; j < 4; ++j) {
      f32x4 z = {0.f, 0.f, 0.f, 0.f};
      acc[i][j] = z;
    }

  // two named A register sets (parity): E holds A(odd-slot), O the next.
  float4 e0lo, e0hi, e1lo, e1hi;
  float4 o0lo, o0hi, o1lo, o1hi;

  // prologue: B(0)->bb0, B(1)->bb1; A(0)->E, convert->ab0; A(1)->E; A(2)->O.
  stage16(Bg0, bb0 + bl0);
  stage16(Bg1, bb0 + bl1);
  stage16(Bg0 + 32, bb1 + bl0);
  stage16(Bg1 + 32, bb1 + bl1);
  e0lo = *(const float4*)Ag0;
  e0hi = *(const float4*)(Ag0 + 4);
  e1lo = *(const float4*)Ag1;
  e1hi = *(const float4*)(Ag1 + 4);
  {
    uint4 u0, u1;
    u0.x = pk2(e0lo.x, e0lo.y); u0.y = pk2(e0lo.z, e0lo.w);
    u0.z = pk2(e0hi.x, e0hi.y); u0.w = pk2(e0hi.z, e0hi.w);
    u1.x = pk2(e1lo.x, e1lo.y); u1.y = pk2(e1lo.z, e1lo.w);
    u1.z = pk2(e1hi.x, e1hi.y); u1.w = pk2(e1hi.z, e1hi.w);
    *(uint4*)&ab0[aoff0] = u0;
    *(uint4*)&ab0[aoff1] = u1;
  }
  // (the A(0)-wait above also drained B(0)/B(1), which are older)
  e0lo = *(const float4*)(Ag0 + 32);
  e0hi = *(const float4*)(Ag0 + 36);
  e1lo = *(const float4*)(Ag1 + 32);
  e1hi = *(const float4*)(Ag1 + 36);
  o0lo = *(const float4*)(Ag0 + 64);
  o0hi = *(const float4*)(Ag0 + 68);
  o1lo = *(const float4*)(Ag1 + 64);
  o1hi = *(const float4*)(Ag1 + 68);
  asm volatile("s_waitcnt lgkmcnt(0)\n\ts_barrier" ::: "memory");

  // main loop, i = 0..27 (A(i+1) convert from set of matching parity;
  // invariant: even i -> E holds A(i+1), odd i -> O holds A(i+1))
  for (int ii = 0; ii < 14; ++ii) {
    const int i0 = 2 * ii;
    QKV_STEP(i0, e0lo, e0hi, e1lo, e1hi, 10)
    QKV_STEP(i0 + 1, o0lo, o0hi, o1lo, o1hi, 10)
  }
  // tail, i = 28..31: in-flight census shrinks -> full drain each iter
  QKV_STEP(28, e0lo, e0hi, e1lo, e1hi, 0)
  QKV_STEP(29, o0lo, o0hi, o1lo, o1hi, 0)
  QKV_STEP(30, e0lo, e0hi, e1lo, e1hi, 0)
  QKV_STEP(31, o0lo, o0hi, o1lo, o1hi, 0)

  float bcol[4];
#pragma unroll
  for (int nt = 0; nt < 4; ++nt) bcol[nt] = bias[n0 + wn + nt * 16 + lr];

  if (vmode == 0) {
#pragma unroll
    for (int mt = 0; mt < 4; ++mt)
#pragma unroll
      for (int nt = 0; nt < 4; ++nt)
#pragma unroll
        for (int r = 0; r < 4; ++r) {
          float v = (acc[mt][nt][r] + bcol[nt]) * oscale;
          int row = m0 + wm + mt * 16 + lg * 4 + r;  // token (b*2048+s)
          int col = n0 + wn + nt * 16 + lr;          // feature (h*64+d)
          int b = row >> 11, ss = row & 2047, hh = col >> 6, d = col & 63;
          Cout[(((size_t)(b * 16 + hh) * 2048 + ss) << 6) + d] = f2b(v);
        }
  } else {
#pragma unroll
    for (int mt = 0; mt < 4; ++mt)
#pragma unroll
      for (int nt = 0; nt < 4; ++nt)
#pragma unroll
        for (int r = 0; r < 4; ++r) {
          float v = acc[mt][nt][r] + bcol[nt];
          int row = m0 + wm + mt * 16 + lg * 4 + r;
          int col = n0 + wn + nt * 16 + lr;
          int b = row >> 11, ss = row & 2047, hh = col >> 6, d = col & 63;
          Cout[(((size_t)(b * 16 + hh) * 64 + d) << 11) + ss] = f2b(v);
        }
  }
}

// ---------------------------------------------------------------------------
// Output GEMM (Wo): C[8192,1024]fp32 = ctx[8192,1024]bf16 @ Wot^T + bias.
// XCD swizzle + T4 counted-vmcnt triple-buffer (unchanged, control).
// ---------------------------------------------------------------------------
__global__ __launch_bounds__(256, 3) void gemm_out(const unsigned short* __restrict__ A,
                                                   const unsigned short* __restrict__ Bt,
                                                   const float* __restrict__ bias,
                                                   float* __restrict__ Cout) {
  const int lid = blockIdx.x + (blockIdx.y << 3);
  const int xcd = lid & 7;
  const int sl = lid >> 3;                // 0..63
  const int tx = sl & 7;
  const int ty = ((sl >> 3) << 3) | xcd;  // 0..63

  __shared__ __align__(16) unsigned short As[3 * 128 * 32];
  __shared__ __align__(16) unsigned short Bs[3 * 128 * 32];
  const int n0 = tx * 128;
  const int m0 = ty * 128;
  const int tid = threadIdx.x;
  const int w = tid >> 6;
  const int lane = tid & 63;
  const int lr = lane & 15;
  const int lg = lane >> 4;
  const int wm = (w >> 1) << 6;
  const int wn = (w & 1) << 6;

  const int srow = w * 16 + (lane >> 2);
  const int sseg = lane & 3;
  const unsigned short* Ag0 = A + (size_t)(m0 + srow) * 1024 + sseg * 8;
  const unsigned short* Ag1 = A + (size_t)(m0 + 64 + srow) * 1024 + sseg * 8;
  const unsigned short* Bg0 = Bt + (size_t)(n0 + srow) * 1024 + sseg * 8;
  const unsigned short* Bg1 = Bt + (size_t)(n0 + 64 + srow) * 1024 + sseg * 8;
  unsigned short *ab0 = &As[0], *ab1 = &As[4096], *ab2 = &As[8192];
  unsigned short *bb0 = &Bs[0], *bb1 = &Bs[4096], *bb2 = &Bs[8192];
  const int hl0 = (w * 16) * 32;
  const int hl1 = (64 + w * 16) * 32;

  f32x4 acc[4][4];
#pragma unroll
  for (int i = 0; i < 4; ++i)
#pragma unroll
    for (int j = 0; j < 4; ++j) {
      f32x4 z = {0.f, 0.f, 0.f, 0.f};
      acc[i][j] = z;
    }

  stage16(Ag0, ab0 + hl0);
  stage16(Ag1, ab0 + hl1);
  stage16(Bg0, bb0 + hl0);
  stage16(Bg1, bb0 + hl1);
  stage16(Ag0 + 32, ab1 + hl0);
  stage16(Ag1 + 32, ab1 + hl1);
  stage16(Bg0 + 32, bb1 + hl0);
  stage16(Bg1 + 32, bb1 + hl1);
  asm volatile("s_waitcnt vmcnt(4)\n\ts_barrier" ::: "memory");

  for (int i = 0; i < 32; ++i) {
    const int k2 = (i + 2) * 32;
    if (i + 2 < 32) {
      stage16(Ag0 + k2, ab2 + hl0);
      stage16(Ag1 + k2, ab2 + hl1);
      stage16(Bg0 + k2, bb2 + hl0);
      stage16(Bg1 + k2, bb2 + hl1);
    }
    s16x8 af[4], bfr[4];
#pragma unroll
    for (int mt = 0; mt < 4; ++mt)
      af[mt] = *(const s16x8*)&ab0[(wm + mt * 16 + lr) * 32 + lg * 8];
#pragma unroll
    for (int nt = 0; nt < 4; ++nt)
      bfr[nt] = *(const s16x8*)&bb0[(wn + nt * 16 + lr) * 32 + lg * 8];
#pragma unroll
    for (int mt = 0; mt < 4; ++mt)
#pragma unroll
      for (int nt = 0; nt < 4; ++nt)
        acc[mt][nt] = MFMA32(af[mt], bfr[nt], acc[mt][nt]);
    asm volatile("s_waitcnt vmcnt(4)\n\ts_barrier" ::: "memory");
    unsigned short* t;
    t = ab0; ab0 = ab1; ab1 = ab2; ab2 = t;
    t = bb0; bb0 = bb1; bb1 = bb2; bb2 = t;
  }

  float bcol[4];
#pragma unroll
  for (int nt = 0; nt < 4; ++nt) bcol[nt] = bias[n0 + wn + nt * 16 + lr];

#pragma unroll
  for (int mt = 0; mt < 4; ++mt)
#pragma unroll
    for (int nt = 0; nt < 4; ++nt)
#pragma unroll
      for (int r = 0; r < 4; ++r) {
        float v = acc[mt][nt][r] + bcol[nt];
        int row = m0 + wm + mt * 16 + lg * 4 + r;
        int col = n0 + wn + nt * 16 + lr;
        Cout[(size_t)row * 1024 + col] = v;
      }
}

// ---------------------------------------------------------------------------
// Flash attention, transposed-S, double-buffered LDS K/V (T3 2-phase pipeline).
// PV + l-sum on 16x16x32 MFMA (round-4-verified slot-permutation layout).
// UNCHANGED (control).
// ---------------------------------------------------------------------------
__global__ __launch_bounds__(256, 4) void flash_attn(const unsigned short* __restrict__ qh,
                                                     const unsigned short* __restrict__ kh,
                                                     const unsigned short* __restrict__ vt,
                                                     const float* __restrict__ mask,
                                                     unsigned short* __restrict__ ctx) {
  const float c2 = 1.4426950408889634e9f;  // 1e9*log2(e)
  const int id = blockIdx.x;
  const int bh = id & 63;
  const int qtile = id >> 6;
  const int b = bh >> 4;
  const int h = bh & 15;
  const int q0 = qtile << 7;
  const int tid = threadIdx.x;
  const int w = tid >> 6;
  const int lane = tid & 63;
  const int lr = lane & 15;
  const int lg = lane >> 4;

  __shared__ __align__(16) unsigned short Ks[2 * 64 * 64];  // [buf][key][d], swizzled segs
  __shared__ __align__(16) unsigned short Vs[2 * 64 * 64];  // [buf][d][key], swizzled segs

  const unsigned short* qbase = qh + ((size_t)bh * 2048 + q0 + w * 32) * 64;
  const unsigned short* kbase = kh + (size_t)bh * 2048 * 64;
  const unsigned short* vbase = vt + (size_t)bh * 64 * 2048;
  const float* mbase = mask + b * 2048;

  const int rowc = lane >> 3;
  const int gseg = (lane & 7) ^ rowc;
  const unsigned short* kg0 = kbase + (size_t)(w * 16 + rowc) * 64 + gseg * 8;
  const unsigned short* kg1 = kbase + (size_t)(w * 16 + 8 + rowc) * 64 + gseg * 8;
  const unsigned short* vg0 = vbase + (size_t)(w * 16 + rowc) * 2048 + gseg * 8;
  const unsigned short* vg1 = vbase + (size_t)(w * 16 + 8 + rowc) * 2048 + gseg * 8;
  unsigned short* kl0 = &Ks[(w * 16 + 0) * 64];
  unsigned short* kl1 = &Ks[(w * 16 + 8) * 64];
  unsigned short* vl0 = &Vs[(w * 16 + 0) * 64];
  unsigned short* vl1 = &Vs[(w * 16 + 8) * 64];

  s16x8 qf[2][2];
#pragma unroll
  for (int qt = 0; qt < 2; ++qt)
#pragma unroll
    for (int kk = 0; kk < 2; ++kk)
      qf[qt][kk] = *(const s16x8*)(qbase + (qt * 16 + lr) * 64 + kk * 32 + lg * 8);

  const s16x8 ones8 = {(short)0x3F80, (short)0x3F80, (short)0x3F80, (short)0x3F80,
                       (short)0x3F80, (short)0x3F80, (short)0x3F80, (short)0x3F80};

  f32x4 o_acc[2][4];
  f32x4 l_acc[2];
#pragma unroll
  for (int qt = 0; qt < 2; ++qt) {
    f32x4 z = {0.f, 0.f, 0.f, 0.f};
    l_acc[qt] = z;
#pragma unroll
    for (int dt = 0; dt < 4; ++dt) o_acc[qt][dt] = z;
  }

  // prologue: stage tile 0 into buffer 0, drain, sync
  stage16(kg0, kl0);
  stage16(kg1, kl1);
  stage16(vg0, vl0);
  stage16(vg1, vl1);
  asm volatile("s_waitcnt vmcnt(0)\n\ts_barrier" ::: "memory");

  int cur = 0;
  for (int t0 = 0; t0 < 2048; t0 += 64) {
    // issue next tile's DMA into the other buffer (in flight during compute)
    if (t0 + 64 < 2048) {
      const int nb = (cur ^ 1) * 4096;
      stage16(kg0 + (size_t)(t0 + 64) * 64, kl0 + nb);
      stage16(kg1 + (size_t)(t0 + 64) * 64, kl1 + nb);
      stage16(vg0 + (t0 + 64), vl0 + nb);
      stage16(vg1 + (t0 + 64), vl1 + nb);
    }
    float4 mk[4];
#pragma unroll
    for (int kt = 0; kt < 4; ++kt) mk[kt] = *(const float4*)(mbase + t0 + kt * 16 + lg * 4);

    const int cb = cur * 4096;
    const int sw = lr & 7;
    // scores -> exp2 -> packed bf16 pairs.
    // pw[kt][qt][u]: keys kt*16 + lg*4 + {2u, 2u+1}, query = lr
    unsigned int pw[4][2][2];
#pragma unroll
    for (int kt = 0; kt < 4; ++kt) {
      const int krow = kt * 16 + lr;
      s16x8 kf0 = *(const s16x8*)&Ks[cb + krow * 64 + ((lg ^ sw) * 8)];
      s16x8 kf1 = *(const s16x8*)&Ks[cb + krow * 64 + (((4 + lg) ^ sw) * 8)];
      float ml0 = mk[kt].x * c2, ml1 = mk[kt].y * c2;
      float ml2 = mk[kt].z * c2, ml3 = mk[kt].w * c2;
#pragma unroll
      for (int qt = 0; qt < 2; ++qt) {
        f32x4 s = {0.f, 0.f, 0.f, 0.f};
        s = MFMA32(kf0, qf[qt][0], s);
        s = MFMA32(kf1, qf[qt][1], s);
        pw[kt][qt][0] = pk2(fast_exp2(s[0] - ml0), fast_exp2(s[1] - ml1));
        pw[kt][qt][1] = pk2(fast_exp2(s[2] - ml2), fast_exp2(s[3] - ml3));
      }
    }

    // PV + l-sum on MFMA32. Chunk c covers keys 32c..32c+31.
    // B position (lg,j) <-> key 32c + (j>=4)*16 + lg*4 + (j&3); V reads match.
#pragma unroll
    for (int c = 0; c < 2; ++c) {
      s16x8 pb[2];
#pragma unroll
      for (int qt = 0; qt < 2; ++qt) {
        uint4 u;
        u.x = pw[2 * c][qt][0];
        u.y = pw[2 * c][qt][1];
        u.z = pw[2 * c + 1][qt][0];
        u.w = pw[2 * c + 1][qt][1];
        pb[qt] = __builtin_bit_cast(s16x8, u);
        l_acc[qt] = MFMA32(ones8, pb[qt], l_acc[qt]);
      }
      const int plo = ((c << 2) | (lg >> 1)) ^ sw;
      const int phi = ((c << 2) | 2 | (lg >> 1)) ^ sw;
      const int sub = (lg & 1) * 4;
#pragma unroll
      for (int dt = 0; dt < 4; ++dt) {
        const int d = dt * 16 + lr;
        s16x4 vlo = *(const s16x4*)&Vs[cb + d * 64 + plo * 8 + sub];
        s16x4 vhi = *(const s16x4*)&Vs[cb + d * 64 + phi * 8 + sub];
        s16x8 vf = __builtin_shufflevector(vlo, vhi, 0, 1, 2, 3, 4, 5, 6, 7);
#pragma unroll
        for (int qt = 0; qt < 2; ++qt) o_acc[qt][dt] = MFMA32(vf, pb[qt], o_acc[qt][dt]);
      }
    }

    // drain next-tile DMA (covered by compute above) + separate buf reuse
    asm volatile("s_waitcnt vmcnt(0)\n\ts_barrier" ::: "memory");
    cur ^= 1;
  }

#pragma unroll
  for (int qt = 0; qt < 2; ++qt) {
    float inv = 1.0f / l_acc[qt][0];
    int q = q0 + w * 32 + qt * 16 + lr;
    unsigned short* cp = ctx + ((size_t)(b * 2048 + q) * 16 + h) * 64 + lg * 4;
#pragma unroll
    for (int dt = 0; dt < 4; ++dt) {
      f32x4 o = o_acc[qt][dt];
      uint2 u;
      u.x = pk2(o[0] * inv, o[1] * inv);
      u.y = pk2(o[2] * inv, o[3] * inv);
      *(uint2*)(cp + dt * 16) = u;
    }
  }
}

// ---------------------------------------------------------------------------
// Launch pipeline. Workspace layout (72 MB):
//   0: wqt 2MB | 2: wkt | 4: wvt | 6: wot          (bf16 W^T [N,K])
//   8: qh 16MB [B,H,S,D] | 24: kh | 40: vt [B,H,D,S] | 56: ctx [B,S,H,D]
// fp32->bf16 cast of Q/K/V is fused into gemm_qkv's A-staging (no scratch).
// ---------------------------------------------------------------------------
extern "C" void kernel_launch(void* const* d_in, const int* in_sizes, int n_in,
                              void* d_out, int out_size, void* d_ws, size_t ws_size,
                              hipStream_t stream) {
  (void)in_sizes; (void)n_in; (void)out_size; (void)ws_size;
  const float* Q = (const float*)d_in[0];
  const float* K = (const float*)d_in[1];
  const float* V = (const float*)d_in[2];
  const float* mask = (const float*)d_in[3];
  const float* Wq = (const float*)d_in[4];
  const float* bq = (const float*)d_in[5];
  const float* Wk = (const float*)d_in[6];
  const float* bk = (const float*)d_in[7];
  const float* Wv = (const float*)d_in[8];
  const float* bv = (const float*)d_in[9];
  const float* Wo = (const float*)d_in[10];
  const float* bo = (const float*)d_in[11];

  char* ws = (char*)d_ws;
  unsigned short* wqt = (unsigned short*)(ws + (size_t)0);
  unsigned short* wkt = (unsigned short*)(ws + ((size_t)2 << 20));
  unsigned short* wvt = (unsigned short*)(ws + ((size_t)4 << 20));
  unsigned short* wot = (unsigned short*)(ws + ((size_t)6 << 20));
  unsigned short* qhb = (unsigned short*)(ws + ((size_t)8 << 20));
  unsigned short* khb = (unsigned short*)(ws + ((size_t)24 << 20));
  unsigned short* vtb = (unsigned short*)(ws + ((size_t)40 << 20));
  unsigned short* ctx = (unsigned short*)(ws + ((size_t)56 << 20));

  wtrans<<<dim3(32, 32, 4), dim3(32, 8), 0, stream>>>(Wq, Wk, Wv, Wo, wqt, wkt, wvt, wot);

  const float qscale = 0.18033688011112042f;  // log2(e)/8, folded into Q projection

  gemm_qkv<<<dim3(8, 64, 3), dim3(256), 0, stream>>>(Q, K, V, wqt, wkt, wvt, bq, bk, bv,
                                                     qhb, khb, vtb, qscale);

  flash_attn<<<dim3(1024), dim3(256), 0, stream>>>(qhb, khb, vtb, mask, ctx);

  gemm_out<<<dim3(8, 64), dim3(256), 0, stream>>>(ctx, wot, bo, (float*)d_out);
}